// Round 2
// baseline (903.455 us; speedup 1.0000x reference)
//
#include <hip/hip_runtime.h>

constexpr int cT  = 1024;
constexpr int cD  = 512;
constexpr int cDK = 64;
constexpr int cP  = 2047;
constexpr int PBS = 1040;   // bf16 prob-buffer row stride (pad 16 -> +8 banks/row)

typedef __attribute__((ext_vector_type(8))) short short8;
typedef __attribute__((ext_vector_type(4))) float floatx4;
typedef __attribute__((ext_vector_type(4))) unsigned int uintx4;

#define MFMA16(a,b,c) __builtin_amdgcn_mfma_f32_16x16x32_bf16((a),(b),(c),0,0,0)
// bijective per-row LDS score layout: conflict-free (2-way) for BOTH the MFMA
// fragment scatter (phase 1/2, lanes vary in l15/lq) and the contiguous-16
// per-lane read (phase 3, lanes vary in lane*16). XOR of j's own high bits
// into the bank bits spreads the 64-byte-per-lane chunks across banks.
#define PHYS(i,j) (((j) ^ ((j) >> 4)) ^ ((((i) >> 2) & 3) << 3))

// barrier that does NOT drain vmcnt: LDS ordering only. Global (NT) stores
// stay in flight across it and drain under later compute (T4 idiom).
__device__ __forceinline__ void bar_lds(){
  asm volatile("s_waitcnt lgkmcnt(0)\n\ts_barrier" ::: "memory");
}

__device__ __forceinline__ unsigned short f2bf(float f){
  union { float f; unsigned int u; } x; x.f = f;
  unsigned int r = x.u + 0x7fffu + ((x.u >> 16) & 1u);   // RNE
  return (unsigned short)(r >> 16);
}
__device__ __forceinline__ float bf2f(unsigned short h){
  union { unsigned int u; float f; } x; x.u = ((unsigned int)h) << 16;
  return x.f;
}
__device__ __forceinline__ short8 ld8(const unsigned short* p){
  return *(const short8*)p;
}

// ---------------- LayerNorm x3 + cast to bf16 ----------------
struct LN3 { const float* x[3]; const float* g[3]; const float* b[3]; unsigned short* y[3]; };
__global__ void __launch_bounds__(256) ln3_kernel(LN3 a)
{
  __shared__ float red[8];
  const int z = blockIdx.y, r = blockIdx.x;
  const float* x = a.x[z]; const float* g = a.g[z]; const float* b = a.b[z];
  unsigned short* y = a.y[z];
  const float2 v = ((const float2*)(x + (size_t)r * cD))[threadIdx.x];
  float s = v.x + v.y, sq = v.x * v.x + v.y * v.y;
  #pragma unroll
  for (int o = 32; o; o >>= 1){ s += __shfl_xor(s, o); sq += __shfl_xor(sq, o); }
  const int w = threadIdx.x >> 6;
  if ((threadIdx.x & 63) == 0){ red[w * 2] = s; red[w * 2 + 1] = sq; }
  __syncthreads();
  s  = red[0] + red[2] + red[4] + red[6];
  sq = red[1] + red[3] + red[5] + red[7];
  const float mu  = s * (1.0f / cD);
  const float var = sq * (1.0f / cD) - mu * mu;
  const float rs  = rsqrtf(var + 1e-5f);
  const int c = threadIdx.x * 2;
  const unsigned int o0 = f2bf((v.x - mu) * rs * g[c]     + b[c]);
  const unsigned int o1 = f2bf((v.y - mu) * rs * g[c + 1] + b[c + 1]);
  ((unsigned int*)(y + (size_t)r * cD))[threadIdx.x] = o0 | (o1 << 16);
}

// ---------------- f32 -> bf16 casts ----------------
struct Ptr5 { const float* p[5]; };
__global__ void __launch_bounds__(256) cast5_kernel(Ptr5 s, unsigned short* __restrict__ d){
  const int idx = blockIdx.x * 256 + threadIdx.x;          // 5 * 262144 total
  const int seg = idx >> 18, off = idx & 262143;
  d[idx] = f2bf(s.p[seg][off]);
}
__global__ void __launch_bounds__(256) cast1_kernel(const float* __restrict__ s,
    unsigned short* __restrict__ d, int n){
  const int idx = blockIdx.x * 256 + threadIdx.x;
  if (idx < n) d[idx] = f2bf(s[idx]);
}

// ---------------- mask -> bitmask: bm[(b*T+t)*32 + w] bit (j&31) = mask!=0 ----------------
__global__ void __launch_bounds__(256) maskbits_kernel(
    const int* __restrict__ mask, unsigned int* __restrict__ bm)
{
  const int row = blockIdx.x * 4 + (threadIdx.x >> 6);
  const int lane = threadIdx.x & 63;
  #pragma unroll
  for (int ii = 0; ii < 16; ii++){
    const int m = mask[(size_t)row * cT + ii * 64 + lane];
    const unsigned long long bal = __ballot(m != 0);
    if (lane == 0)       bm[row * 32 + ii * 2]     = (unsigned int)bal;
    else if (lane == 32) bm[row * 32 + ii * 2 + 1] = (unsigned int)(bal >> 32);
  }
}

// ---------------- GEMM: Y[r][o] = scale * sum_k A[r][k] * W[o][k]; K=N=512 ------------
// fused==1: A/W/outb advance by blockIdx.z (QKV); scaleA applies to z==0 only.
// mode 0: outb[((b*8+h)*1024+t)*64+d] bf16 ; mode 1: outb[(h*2047+r)*64+d] bf16
// mode 2: outf[r*512+o] = acc + residual[r*512+o] (f32 final output)
__global__ void __launch_bounds__(256) gemm512_kernel(
    const unsigned short* __restrict__ A0, const unsigned short* __restrict__ W0,
    int M, int mode, float scaleA, unsigned short* __restrict__ outb,
    float* __restrict__ outf, const float* __restrict__ residual)
{
  const int z = blockIdx.z;
  const unsigned short* A = A0 + (size_t)z * 4194304;
  const unsigned short* W = W0 + (size_t)z * 262144;
  unsigned short* outz = outb ? outb + (size_t)z * 4194304 : outb;
  const float sA = (z == 0) ? scaleA : 1.0f;
  const int n0 = blockIdx.x * 128, m0 = blockIdx.y * 128;
  const int wave = threadIdx.x >> 6, lane = threadIdx.x & 63;
  const int wr = wave >> 1, wc = wave & 1;
  const int l15 = lane & 15, lq = lane >> 4;
  const int mb = m0 + wr * 64, nb = n0 + wc * 64;
  floatx4 acc[4][4];
  #pragma unroll
  for (int i = 0; i < 4; i++)
    #pragma unroll
    for (int j = 0; j < 4; j++) acc[i][j] = (floatx4){0.f, 0.f, 0.f, 0.f};
  for (int k0 = 0; k0 < 512; k0 += 32){
    short8 af[4], bf[4];
    #pragma unroll
    for (int i = 0; i < 4; i++){
      int row = mb + i * 16 + l15; if (row >= M) row = M - 1;
      af[i] = ld8(A + (size_t)row * 512 + k0 + lq * 8);
      const int col = nb + i * 16 + l15;
      bf[i] = ld8(W + (size_t)col * 512 + k0 + lq * 8);
    }
    #pragma unroll
    for (int i = 0; i < 4; i++)
      #pragma unroll
      for (int j = 0; j < 4; j++)
        acc[i][j] = MFMA16(af[i], bf[j], acc[i][j]);
  }
  #pragma unroll
  for (int i = 0; i < 4; i++){
    #pragma unroll
    for (int j = 0; j < 4; j++){
      #pragma unroll
      for (int r = 0; r < 4; r++){
        const int row = mb + i * 16 + lq * 4 + r;
        const int col = nb + j * 16 + l15;
        if (row >= M) continue;
        const float val = acc[i][j][r] * sA;
        if (mode == 0){
          const int bb = row >> 10, t = row & 1023, h = col >> 6, d = col & 63;
          outz[(((size_t)(bb * 8 + h) * 1024 + t) << 6) + d] = f2bf(val);
        } else if (mode == 1){
          const int h = col >> 6, d = col & 63;
          outz[(((size_t)h * 2047 + row) << 6) + d] = f2bf(val);
        } else {
          const size_t idx = (size_t)row * 512 + col;
          outf[idx] = val + residual[idx];
        }
      }
    }
  }
}

// ---------------- V transpose: [BH,T,64] -> [BH,64,T] ----------------
__global__ void __launch_bounds__(256) transpose_v_kernel(
    const unsigned short* __restrict__ vh, unsigned short* __restrict__ vt)
{
  __shared__ unsigned short tile[64][65];
  const int bh = blockIdx.x, t0 = blockIdx.y * 64;
  const unsigned short* src = vh + ((size_t)bh * cT + t0) * cDK;
  #pragma unroll
  for (int i = 0; i < 16; i++){
    const int idx = threadIdx.x + i * 256;
    tile[idx >> 6][idx & 63] = src[idx];
  }
  __syncthreads();
  unsigned short* dst = vt + (size_t)bh * cDK * cT + t0;
  #pragma unroll
  for (int i = 0; i < 16; i++){
    const int idx = threadIdx.x + i * 256;
    const int d = idx >> 6, t = idx & 63;
    dst[(size_t)d * cT + t] = tile[t][d];
  }
}

// ---------------- per-key bias: out[row] = scale * dot64(bias[h], X[row]) ----------------
__global__ void __launch_bounds__(256) dot_bias_kernel(
    const unsigned short* __restrict__ X, const float* __restrict__ bias,
    float* __restrict__ out, int rows, int hdiv, float scale)
{
  const int row = blockIdx.x * 4 + (threadIdx.x >> 6);
  const int lane = threadIdx.x & 63;
  if (row >= rows) return;
  const int h = (row / hdiv) & 7;
  float s = bf2f(X[(size_t)row * 64 + lane]) * bias[h * 64 + lane];
  #pragma unroll
  for (int o = 32; o; o >>= 1) s += __shfl_xor(s, o);
  if (lane == 0) out[row] = s * scale;
}

// ---------------- fused relpos attention: block = (b,h, 16 q-rows), 8 waves ----------------
// scale (1/8) pre-folded into qh / ubias / vbias.
// 512 threads, 64 KiB LDS -> 2 blocks/CU, 16 waves/CU.
// Barriers are lgkm-only (bar_lds): the 268 MB of NT attn stores never drain
// at a barrier -- they stay in flight under later phases / across blocks.
__global__ void __launch_bounds__(512, 4) attn_kernel(
    const unsigned short* __restrict__ qh, const unsigned short* __restrict__ kh,
    const unsigned short* __restrict__ vt, const unsigned short* __restrict__ pproj,
    const float* __restrict__ ubias, const float* __restrict__ vbias,
    const unsigned int* __restrict__ bm, float* __restrict__ attn_out,
    unsigned short* __restrict__ out_h)
{
  __shared__ float sc[16 * cT];                 // 64 KiB f32 scores
  unsigned short* pbuf = (unsigned short*)sc;   // bf16 [16][PBS] overlay (33,248 B), used after
  const int bh = blockIdx.x, b = bh >> 3, h = bh & 7;
  const int q0 = blockIdx.y * 16;
  const int wave = threadIdx.x >> 6, lane = threadIdx.x & 63;
  const int l15 = lane & 15, lq = lane >> 4;
  const unsigned short* Q  = qh + (size_t)bh * cT * cDK;
  const unsigned short* Kp = kh + (size_t)bh * cT * cDK;
  const unsigned short* Pt = pproj + (size_t)h * cP * cDK;
  const float* ub = ubias + (size_t)bh * cT;
  const float* vb = vbias + (size_t)h * cP;

  const short8 qf0 = ld8(Q + (size_t)(q0 + l15) * cDK + lq * 8);
  const short8 qf1 = ld8(Q + (size_t)(q0 + l15) * cDK + 32 + lq * 8);

  // ---- phase 1: ac = Q K^T + ub + vb -> LDS (biases folded here: their access
  // pattern is contiguous per MFMA column, vs 64-line scatter in phase 3) ----
  for (int jt = wave; jt < 64; jt += 8){
    const short8 kf0 = ld8(Kp + (size_t)(jt * 16 + l15) * cDK + lq * 8);
    const short8 kf1 = ld8(Kp + (size_t)(jt * 16 + l15) * cDK + 32 + lq * 8);
    floatx4 acc = (floatx4){0.f, 0.f, 0.f, 0.f};
    acc = MFMA16(qf0, kf0, acc);
    acc = MFMA16(qf1, kf1, acc);
    const int jb = jt * 16 + l15;
    const float ubv = ub[jb];
    #pragma unroll
    for (int r = 0; r < 4; r++){
      const int i = lq * 4 + r;
      sc[i * cT + PHYS(i, jb)] = acc[r] + ubv + vb[jb + (cT - 1) - (q0 + i)];
    }
  }
  bar_lds();

  // ---- phase 2: bd window GEMM, diagonal scatter-add  j = c - 15 + i ----
  const int w0 = (cT - 1) - q0 - 15;
  for (int ct = wave; ct < 65; ct += 8){
    const int c = ct * 16 + l15;
    int prow = w0 + c; if (prow > cP - 1) prow = cP - 1;  // clamped rows -> j>=1024, dropped
    const short8 pf0 = ld8(Pt + (size_t)prow * cDK + lq * 8);
    const short8 pf1 = ld8(Pt + (size_t)prow * cDK + 32 + lq * 8);
    floatx4 acc = (floatx4){0.f, 0.f, 0.f, 0.f};
    acc = MFMA16(qf0, pf0, acc);
    acc = MFMA16(qf1, pf1, acc);
    #pragma unroll
    for (int r = 0; r < 4; r++){
      const int i = lq * 4 + r;
      const int j = c - 15 + i;
      if (j >= 0 && j < cT) sc[i * cT + PHYS(i, j)] += acc[r];
    }
  }
  bar_lds();

  // ---- phase 3: masked softmax. Contiguous-16 ownership: lane owns
  // j in [16*lane, 16*lane+16). One bm word / 4 NT dwordx4 stores / 2 b128
  // pbuf writes per row. Wave handles rows 2*wave, 2*wave+1.
  // pbuf overlay safety: ALL sc reads (rows 0-15) complete before the single
  // barrier; writes after it touch only pbuf bytes [0, 33248) = sc rows 0-8.13.
  const int jb = lane * 16;
  float vals[2][16];
  float rcp[2];
  #pragma unroll
  for (int rr = 0; rr < 2; rr++){
    const int i = wave * 2 + rr;
    const int qrow = q0 + i;
    const unsigned int mw = bm[((size_t)b * cT + qrow) * 32 + (lane >> 1)];
    const int msh = (lane & 1) * 16;
    float mx = -INFINITY;
    #pragma unroll
    for (int ii = 0; ii < 16; ii++){
      float s = sc[i * cT + PHYS(i, jb + ii)];
      if (((mw >> (msh + ii)) & 1u) == 0u) s = -INFINITY;
      vals[rr][ii] = s;
      mx = fmaxf(mx, s);
    }
    #pragma unroll
    for (int o = 32; o; o >>= 1) mx = fmaxf(mx, __shfl_xor(mx, o));
    float sum = 0.f;
    #pragma unroll
    for (int ii = 0; ii < 16; ii++){
      const float e = (vals[rr][ii] == -INFINITY) ? 0.f : __expf(vals[rr][ii] - mx);
      vals[rr][ii] = e; sum += e;
    }
    #pragma unroll
    for (int o = 32; o; o >>= 1) sum += __shfl_xor(sum, o);
    rcp[rr] = sum > 0.f ? 1.f / sum : 0.f;
  }
  bar_lds();            // all sc reads complete; NT stores not yet issued
  #pragma unroll
  for (int rr = 0; rr < 2; rr++){
    const int i = wave * 2 + rr;
    const int qrow = q0 + i;
    #pragma unroll
    for (int ii = 0; ii < 16; ii++) vals[rr][ii] *= rcp[rr];
    // bf16 pack -> pbuf (two 16B LDS writes)
    uintx4 w0v, w1v;
    #pragma unroll
    for (int t = 0; t < 4; t++)
      w0v[t] = (unsigned int)f2bf(vals[rr][2 * t]) |
               ((unsigned int)f2bf(vals[rr][2 * t + 1]) << 16);
    #pragma unroll
    for (int t = 0; t < 4; t++)
      w1v[t] = (unsigned int)f2bf(vals[rr][8 + 2 * t]) |
               ((unsigned int)f2bf(vals[rr][8 + 2 * t + 1]) << 16);
    uintx4* pw = (uintx4*)(pbuf + (size_t)i * PBS + jb);
    pw[0] = w0v; pw[1] = w1v;
    // f32 NT stores (4 x dwordx4, 64B per lane, fully coalesced)
    float* arow = attn_out + ((size_t)bh * cT + qrow) * cT + jb;
    #pragma unroll
    for (int t = 0; t < 4; t++){
      floatx4 pv = (floatx4){ vals[rr][4 * t], vals[rr][4 * t + 1],
                              vals[rr][4 * t + 2], vals[rr][4 * t + 3] };
      __builtin_nontemporal_store(pv, (floatx4*)arow + t);
    }
  }
  bar_lds();            // pbuf visible; NT stores still in flight

  // ---- phase 4: O = P V via ds_read_b128 bf16 fragments; keys split across wave halves ----
  const unsigned short* V = vt + (size_t)bh * cDK * cT;
  const int d0 = (wave & 3) * 16;
  const int kh2 = wave >> 2;                    // 0: keys 0-511, 1: keys 512-1023
  floatx4 acc = (floatx4){0.f, 0.f, 0.f, 0.f};
  for (int ks = 0; ks < 16; ks++){
    const int j0 = (kh2 * 16 + ks) * 32;
    const short8 vf = ld8(V + (size_t)(d0 + l15) * cT + j0 + lq * 8);
    const short8 af = ld8(pbuf + l15 * PBS + j0 + lq * 8);
    acc = MFMA16(af, vf, acc);
  }
  // combine halves via 4 KiB LDS scratch past the pbuf overlay (byte 40960)
  float* red4 = sc + 10240;
  if (kh2 == 1) *(floatx4*)(red4 + ((wave & 3) * 256 + lane * 4)) = acc;
  bar_lds();
  if (kh2 == 0){
    acc += *(const floatx4*)(red4 + ((wave & 3) * 256 + lane * 4));
    #pragma unroll
    for (int r = 0; r < 4; r++){
      const int i = lq * 4 + r;
      out_h[((size_t)b * cT + q0 + i) * cD + h * cDK + d0 + l15] = f2bf(acc[r]);
    }
  }
}

// ---------------- host launcher ----------------
extern "C" void kernel_launch(void* const* d_in, const int* in_sizes, int n_in,
                              void* d_out, int out_size, void* d_ws, size_t ws_size,
                              hipStream_t stream)
{
  const float* q    = (const float*)d_in[0];
  const float* k    = (const float*)d_in[1];
  const float* v    = (const float*)d_in[2];
  const float* pe   = (const float*)d_in[3];
  const int*   mask = (const int*)d_in[4];
  const float* lnqg = (const float*)d_in[5];
  const float* lnqb = (const float*)d_in[6];
  const float* lnkg = (const float*)d_in[7];
  const float* lnkb = (const float*)d_in[8];
  const float* lnvg = (const float*)d_in[9];
  const float* lnvb = (const float*)d_in[10];
  const float* wq   = (const float*)d_in[11];
  const float* wk   = (const float*)d_in[12];
  const float* wv   = (const float*)d_in[13];
  const float* wpos = (const float*)d_in[14];
  const float* wfc  = (const float*)d_in[15];
  const float* pbu  = (const float*)d_in[16];
  const float* pbv  = (const float*)d_in[17];

  float* out_f  = (float*)d_out;                       // [8,1024,512] f32
  float* attn_f = out_f + (size_t)8 * 1024 * 512;      // [8,8,1024,1024] f32, 268 MB

  // --- scratch dead before attn_kernel lives inside the attn output region ---
  unsigned char* scr = (unsigned char*)attn_f;
  size_t soff = 0;
  auto salloc = [&](size_t bytes){ void* p = scr + soff; soff += (bytes + 255) & ~(size_t)255; return p; };
  unsigned short* qn   = (unsigned short*)salloc((size_t)8192 * 512 * 2);  // qn,kn,vn consecutive
  unsigned short* kn   = (unsigned short*)salloc((size_t)8192 * 512 * 2);
  unsigned short* vn   = (unsigned short*)salloc((size_t)8192 * 512 * 2);
  unsigned short* pe_b = (unsigned short*)salloc((size_t)2047 * 512 * 2);
  (void)kn; (void)vn;

  // --- workspace: buffers that live across / after attn_kernel (~46 MB) ---
  unsigned char* ws = (unsigned char*)d_ws;
  size_t off = 0;
  auto alloc = [&](size_t bytes){ void* p = ws + off; off += (bytes + 255) & ~(size_t)255; return p; };
  unsigned short* w5_b = (unsigned short*)alloc(5 * 512 * 512 * 2);        // wq,wk,wv,wpos,wfc
  unsigned short* qhb  = (unsigned short*)alloc((size_t)8192 * 512 * 2);   // qhb,khb,vhb consecutive
  unsigned short* khb  = (unsigned short*)alloc((size_t)8192 * 512 * 2);
  unsigned short* vhb  = (unsigned short*)alloc((size_t)8192 * 512 * 2);
  unsigned short* vtb  = (unsigned short*)alloc((size_t)8192 * 512 * 2);   // [B,H,64,T]
  unsigned short* ppb  = (unsigned short*)alloc((size_t)8 * 2047 * 64 * 2);// [H,P,64]
  float*          ub   = (float*)alloc((size_t)8 * 8 * 1024 * 4);          // [B,H,T]
  float*          vbias= (float*)alloc((size_t)8 * 2047 * 4);              // [H,P]
  unsigned short* ohb  = (unsigned short*)alloc((size_t)8192 * 512 * 2);   // [B,T,512]
  unsigned int*   bmask= (unsigned int*)alloc((size_t)8192 * 32 * 4);      // [B,T,32]
  (void)ws_size; (void)n_in; (void)in_sizes; (void)out_size;

  Ptr5 c5; c5.p[0] = wq; c5.p[1] = wk; c5.p[2] = wv; c5.p[3] = wpos; c5.p[4] = wfc;
  cast5_kernel<<<5120, 256, 0, stream>>>(c5, w5_b);
  cast1_kernel<<<4094, 256, 0, stream>>>(pe, pe_b, 2047 * 512);
  maskbits_kernel<<<2048, 256, 0, stream>>>(mask, bmask);

  LN3 l3;
  l3.x[0] = q; l3.x[1] = k; l3.x[2] = v;
  l3.g[0] = lnqg; l3.g[1] = lnkg; l3.g[2] = lnvg;
  l3.b[0] = lnqb; l3.b[1] = lnkb; l3.b[2] = lnvb;
  l3.y[0] = qn; l3.y[1] = kn; l3.y[2] = vn;
  ln3_kernel<<<dim3(8192, 3), 256, 0, stream>>>(l3);

  // fused QKV projections (z=0:q scaled by 1/8, z=1:k, z=2:v)
  gemm512_kernel<<<dim3(4, 64, 3), 256, 0, stream>>>(qn, w5_b, 8192, 0, 0.125f,
                                                     qhb, nullptr, nullptr);
  gemm512_kernel<<<dim3(4, 16, 1), 256, 0, stream>>>(pe_b, w5_b + 3 * 262144, 2047, 1, 1.0f,
                                                     ppb, nullptr, nullptr);

  transpose_v_kernel<<<dim3(64, 16), 256, 0, stream>>>(vhb, vtb);

  dot_bias_kernel<<<16384, 256, 0, stream>>>(khb, pbu, ub, 65536, 1024, 0.125f);
  dot_bias_kernel<<<4094, 256, 0, stream>>>(ppb, pbv, vbias, 16376, 2047, 0.125f);

  attn_kernel<<<dim3(64, 64), 512, 0, stream>>>(qhb, khb, vtb, ppb, ub, vbias,
                                                bmask, attn_f, ohb);

  gemm512_kernel<<<dim3(4, 64, 1), 256, 0, stream>>>(ohb, w5_b + 4 * 262144, 8192, 2, 1.0f,
                                                     nullptr, out_f, q);
}

// Round 3
// 722.112 us; speedup vs baseline: 1.2511x; 1.2511x over previous
//
#include <hip/hip_runtime.h>

constexpr int cT  = 1024;
constexpr int cD  = 512;
constexpr int cDK = 64;
constexpr int cP  = 2047;
constexpr int PBS = 1040;   // bf16 prob-buffer row stride (pad 16 -> +8 banks/row)

typedef __attribute__((ext_vector_type(8))) short short8;
typedef __attribute__((ext_vector_type(4))) float floatx4;

#define MFMA16(a,b,c) __builtin_amdgcn_mfma_f32_16x16x32_bf16((a),(b),(c),0,0,0)
// swizzle keyed on i>>2 (varies across lanes within a store), not i&3 (constant)
#define SWZ(i,j) ((j) ^ ((((i) >> 2) & 3) << 3))

// barrier that does NOT drain vmcnt: LDS ordering only. Global (NT) stores
// stay in flight across it and drain under later compute (T4 idiom).
__device__ __forceinline__ void bar_lds(){
  asm volatile("s_waitcnt lgkmcnt(0)\n\ts_barrier" ::: "memory");
}

__device__ __forceinline__ unsigned short f2bf(float f){
  union { float f; unsigned int u; } x; x.f = f;
  unsigned int r = x.u + 0x7fffu + ((x.u >> 16) & 1u);   // RNE
  return (unsigned short)(r >> 16);
}
__device__ __forceinline__ float bf2f(unsigned short h){
  union { unsigned int u; float f; } x; x.u = ((unsigned int)h) << 16;
  return x.f;
}
__device__ __forceinline__ short8 ld8(const unsigned short* p){
  return *(const short8*)p;
}

// ---------------- LayerNorm x3 + cast to bf16 ----------------
struct LN3 { const float* x[3]; const float* g[3]; const float* b[3]; unsigned short* y[3]; };
__global__ void __launch_bounds__(256) ln3_kernel(LN3 a)
{
  __shared__ float red[8];
  const int z = blockIdx.y, r = blockIdx.x;
  const float* x = a.x[z]; const float* g = a.g[z]; const float* b = a.b[z];
  unsigned short* y = a.y[z];
  const float2 v = ((const float2*)(x + (size_t)r * cD))[threadIdx.x];
  float s = v.x + v.y, sq = v.x * v.x + v.y * v.y;
  #pragma unroll
  for (int o = 32; o; o >>= 1){ s += __shfl_xor(s, o); sq += __shfl_xor(sq, o); }
  const int w = threadIdx.x >> 6;
  if ((threadIdx.x & 63) == 0){ red[w * 2] = s; red[w * 2 + 1] = sq; }
  __syncthreads();
  s  = red[0] + red[2] + red[4] + red[6];
  sq = red[1] + red[3] + red[5] + red[7];
  const float mu  = s * (1.0f / cD);
  const float var = sq * (1.0f / cD) - mu * mu;
  const float rs  = rsqrtf(var + 1e-5f);
  const int c = threadIdx.x * 2;
  const unsigned int o0 = f2bf((v.x - mu) * rs * g[c]     + b[c]);
  const unsigned int o1 = f2bf((v.y - mu) * rs * g[c + 1] + b[c + 1]);
  ((unsigned int*)(y + (size_t)r * cD))[threadIdx.x] = o0 | (o1 << 16);
}

// ---------------- f32 -> bf16 casts ----------------
struct Ptr5 { const float* p[5]; };
__global__ void __launch_bounds__(256) cast5_kernel(Ptr5 s, unsigned short* __restrict__ d){
  const int idx = blockIdx.x * 256 + threadIdx.x;          // 5 * 262144 total
  const int seg = idx >> 18, off = idx & 262143;
  d[idx] = f2bf(s.p[seg][off]);
}
__global__ void __launch_bounds__(256) cast1_kernel(const float* __restrict__ s,
    unsigned short* __restrict__ d, int n){
  const int idx = blockIdx.x * 256 + threadIdx.x;
  if (idx < n) d[idx] = f2bf(s[idx]);
}

// ---------------- mask -> bitmask: bm[(b*T+t)*32 + w] bit (j&31) = mask!=0 ----------------
__global__ void __launch_bounds__(256) maskbits_kernel(
    const int* __restrict__ mask, unsigned int* __restrict__ bm)
{
  const int row = blockIdx.x * 4 + (threadIdx.x >> 6);
  const int lane = threadIdx.x & 63;
  #pragma unroll
  for (int ii = 0; ii < 16; ii++){
    const int m = mask[(size_t)row * cT + ii * 64 + lane];
    const unsigned long long bal = __ballot(m != 0);
    if (lane == 0)       bm[row * 32 + ii * 2]     = (unsigned int)bal;
    else if (lane == 32) bm[row * 32 + ii * 2 + 1] = (unsigned int)(bal >> 32);
  }
}

// ---------------- GEMM: Y[r][o] = scale * sum_k A[r][k] * W[o][k]; K=N=512 ------------
// fused==1: A/W/outb advance by blockIdx.z (QKV); scaleA applies to z==0 only.
// mode 0: outb[((b*8+h)*1024+t)*64+d] bf16 ; mode 1: outb[(h*2047+r)*64+d] bf16
// mode 2: outf[r*512+o] = acc + residual[r*512+o] (f32 final output)
__global__ void __launch_bounds__(256) gemm512_kernel(
    const unsigned short* __restrict__ A0, const unsigned short* __restrict__ W0,
    int M, int mode, float scaleA, unsigned short* __restrict__ outb,
    float* __restrict__ outf, const float* __restrict__ residual)
{
  const int z = blockIdx.z;
  const unsigned short* A = A0 + (size_t)z * 4194304;
  const unsigned short* W = W0 + (size_t)z * 262144;
  unsigned short* outz = outb ? outb + (size_t)z * 4194304 : outb;
  const float sA = (z == 0) ? scaleA : 1.0f;
  const int n0 = blockIdx.x * 128, m0 = blockIdx.y * 128;
  const int wave = threadIdx.x >> 6, lane = threadIdx.x & 63;
  const int wr = wave >> 1, wc = wave & 1;
  const int l15 = lane & 15, lq = lane >> 4;
  const int mb = m0 + wr * 64, nb = n0 + wc * 64;
  floatx4 acc[4][4];
  #pragma unroll
  for (int i = 0; i < 4; i++)
    #pragma unroll
    for (int j = 0; j < 4; j++) acc[i][j] = (floatx4){0.f, 0.f, 0.f, 0.f};
  for (int k0 = 0; k0 < 512; k0 += 32){
    short8 af[4], bf[4];
    #pragma unroll
    for (int i = 0; i < 4; i++){
      int row = mb + i * 16 + l15; if (row >= M) row = M - 1;
      af[i] = ld8(A + (size_t)row * 512 + k0 + lq * 8);
      const int col = nb + i * 16 + l15;
      bf[i] = ld8(W + (size_t)col * 512 + k0 + lq * 8);
    }
    #pragma unroll
    for (int i = 0; i < 4; i++)
      #pragma unroll
      for (int j = 0; j < 4; j++)
        acc[i][j] = MFMA16(af[i], bf[j], acc[i][j]);
  }
  #pragma unroll
  for (int i = 0; i < 4; i++){
    #pragma unroll
    for (int j = 0; j < 4; j++){
      #pragma unroll
      for (int r = 0; r < 4; r++){
        const int row = mb + i * 16 + lq * 4 + r;
        const int col = nb + j * 16 + l15;
        if (row >= M) continue;
        const float val = acc[i][j][r] * sA;
        if (mode == 0){
          const int bb = row >> 10, t = row & 1023, h = col >> 6, d = col & 63;
          outz[(((size_t)(bb * 8 + h) * 1024 + t) << 6) + d] = f2bf(val);
        } else if (mode == 1){
          const int h = col >> 6, d = col & 63;
          outz[(((size_t)h * 2047 + row) << 6) + d] = f2bf(val);
        } else {
          const size_t idx = (size_t)row * 512 + col;
          outf[idx] = val + residual[idx];
        }
      }
    }
  }
}

// ---------------- V transpose: [BH,T,64] -> [BH,64,T] ----------------
__global__ void __launch_bounds__(256) transpose_v_kernel(
    const unsigned short* __restrict__ vh, unsigned short* __restrict__ vt)
{
  __shared__ unsigned short tile[64][65];
  const int bh = blockIdx.x, t0 = blockIdx.y * 64;
  const unsigned short* src = vh + ((size_t)bh * cT + t0) * cDK;
  #pragma unroll
  for (int i = 0; i < 16; i++){
    const int idx = threadIdx.x + i * 256;
    tile[idx >> 6][idx & 63] = src[idx];
  }
  __syncthreads();
  unsigned short* dst = vt + (size_t)bh * cDK * cT + t0;
  #pragma unroll
  for (int i = 0; i < 16; i++){
    const int idx = threadIdx.x + i * 256;
    const int d = idx >> 6, t = idx & 63;
    dst[(size_t)d * cT + t] = tile[t][d];
  }
}

// ---------------- per-key bias: out[row] = scale * dot64(bias[h], X[row]) ----------------
__global__ void __launch_bounds__(256) dot_bias_kernel(
    const unsigned short* __restrict__ X, const float* __restrict__ bias,
    float* __restrict__ out, int rows, int hdiv, float scale)
{
  const int row = blockIdx.x * 4 + (threadIdx.x >> 6);
  const int lane = threadIdx.x & 63;
  if (row >= rows) return;
  const int h = (row / hdiv) & 7;
  float s = bf2f(X[(size_t)row * 64 + lane]) * bias[h * 64 + lane];
  #pragma unroll
  for (int o = 32; o; o >>= 1) s += __shfl_xor(s, o);
  if (lane == 0) out[row] = s * scale;
}

// ---------------- fused relpos attention: block = (b,h, 16 q-rows), 8 waves ----------------
// scale (1/8) pre-folded into qh / ubias / vbias.
// 512 threads, 64 KiB LDS -> 2 blocks/CU, 16 waves/CU.
// Barriers are lgkm-only (bar_lds): the 268 MB of NT attn stores never drain
// at a barrier -- they stay in flight under later phases / across blocks.
// Phase-3 store pattern: per-lane INTERLEAVED (j = lane + ii*64) -> every NT
// store instruction covers 4 full 64B lines (round-2's contiguous-16 pattern
// caused 2.7x write amplification via partial-line NT writes).
__global__ void __launch_bounds__(512, 4) attn_kernel(
    const unsigned short* __restrict__ qh, const unsigned short* __restrict__ kh,
    const unsigned short* __restrict__ vt, const unsigned short* __restrict__ pproj,
    const float* __restrict__ ubias, const float* __restrict__ vbias,
    const unsigned int* __restrict__ bm, float* __restrict__ attn_out,
    unsigned short* __restrict__ out_h)
{
  __shared__ float sc[16 * cT];                 // 64 KiB f32 scores
  unsigned short* pbuf = (unsigned short*)sc;   // bf16 [16][PBS] overlay (33,248 B), used after
  const int bh = blockIdx.x, b = bh >> 3, h = bh & 7;
  const int q0 = blockIdx.y * 16;
  const int wave = threadIdx.x >> 6, lane = threadIdx.x & 63;
  const int l15 = lane & 15, lq = lane >> 4;
  const unsigned short* Q  = qh + (size_t)bh * cT * cDK;
  const unsigned short* Kp = kh + (size_t)bh * cT * cDK;
  const unsigned short* Pt = pproj + (size_t)h * cP * cDK;
  const float* ub = ubias + (size_t)bh * cT;
  const float* vb = vbias + (size_t)h * cP;

  const short8 qf0 = ld8(Q + (size_t)(q0 + l15) * cDK + lq * 8);
  const short8 qf1 = ld8(Q + (size_t)(q0 + l15) * cDK + 32 + lq * 8);

  // ---- phase 1: ac = Q K^T + ub + vb -> LDS (2-way banks via SWZ; biases
  // folded here where the access pattern is contiguous per MFMA column) ----
  for (int jt = wave; jt < 64; jt += 8){
    const short8 kf0 = ld8(Kp + (size_t)(jt * 16 + l15) * cDK + lq * 8);
    const short8 kf1 = ld8(Kp + (size_t)(jt * 16 + l15) * cDK + 32 + lq * 8);
    floatx4 acc = (floatx4){0.f, 0.f, 0.f, 0.f};
    acc = MFMA16(qf0, kf0, acc);
    acc = MFMA16(qf1, kf1, acc);
    const int jb = jt * 16 + l15;
    const float ubv = ub[jb];
    #pragma unroll
    for (int r = 0; r < 4; r++){
      const int i = lq * 4 + r;
      sc[i * cT + (jb ^ (lq << 3))] = acc[r] + ubv + vb[jb + (cT - 1) - (q0 + i)];
    }
  }
  bar_lds();

  // ---- phase 2: bd window GEMM, diagonal scatter-add  j = c - 15 + i ----
  const int w0 = (cT - 1) - q0 - 15;
  for (int ct = wave; ct < 65; ct += 8){
    const int c = ct * 16 + l15;
    int prow = w0 + c; if (prow > cP - 1) prow = cP - 1;  // clamped rows -> j>=1024, dropped
    const short8 pf0 = ld8(Pt + (size_t)prow * cDK + lq * 8);
    const short8 pf1 = ld8(Pt + (size_t)prow * cDK + 32 + lq * 8);
    floatx4 acc = (floatx4){0.f, 0.f, 0.f, 0.f};
    acc = MFMA16(qf0, pf0, acc);
    acc = MFMA16(qf1, pf1, acc);
    #pragma unroll
    for (int r = 0; r < 4; r++){
      const int i = lq * 4 + r;
      const int j = c - 15 + i;
      if (j >= 0 && j < cT) sc[i * cT + SWZ(i, j)] += acc[r];
    }
  }
  bar_lds();

  // ---- phase 3: masked softmax, 2 passes (read | barrier | write), 8 rows/pass ----
  // pass p: wave w handles row i = 8p + w. pbuf writes of pass p only touch sc
  // bytes whose rows were fully consumed by all waves before pass p's barrier:
  //   pass 0 writes pbuf rows 0-7  = bytes [0, 16608)      -> sc rows 0-4.05 (read in pass 0)
  //   pass 1 writes pbuf rows 8-15 = bytes [16640, 33248)  -> sc rows 4.06-8.1 (rows 4-7 read
  //   in pass 0; sc row 8's first 480 B read in pass 1 by wave 0 before the pass-1 barrier)
  for (int p = 0; p < 2; p++){
    const int i = p * 8 + wave;
    const int qrow = q0 + i;
    const unsigned int* bmr = bm + ((size_t)b * cT + qrow) * 32;
    float vals[16];
    float mx = -INFINITY;
    #pragma unroll
    for (int ii = 0; ii < 16; ii++){
      const int j = lane + ii * 64;
      float s = sc[i * cT + SWZ(i, j)];
      const unsigned int mw = bmr[ii * 2 + (lane >> 5)];
      if (((mw >> (lane & 31)) & 1u) == 0u) s = -INFINITY;
      vals[ii] = s;
      mx = fmaxf(mx, s);
    }
    #pragma unroll
    for (int o = 32; o; o >>= 1) mx = fmaxf(mx, __shfl_xor(mx, o));
    float sum = 0.f;
    #pragma unroll
    for (int ii = 0; ii < 16; ii++){
      const float e = (vals[ii] == -INFINITY) ? 0.f : __expf(vals[ii] - mx);
      vals[ii] = e; sum += e;
    }
    #pragma unroll
    for (int o = 32; o; o >>= 1) sum += __shfl_xor(sum, o);
    const float ri = sum > 0.f ? 1.f / sum : 0.f;
    bar_lds();            // all sc reads of rows 8p..8p+7 complete (lgkm only)
    float* arow = attn_out + ((size_t)bh * cT + qrow) * cT;
    #pragma unroll
    for (int ii = 0; ii < 16; ii++){
      const int j = lane + ii * 64;
      const float pr = vals[ii] * ri;
      __builtin_nontemporal_store(pr, arow + j);   // full-line coalesced, stays in flight
      pbuf[i * PBS + j] = f2bf(pr);                // 2-way banks (pairs share a word)
    }
  }
  bar_lds();

  // ---- phase 4: O = P V via ds_read_b128 bf16 fragments; keys split across wave halves ----
  const unsigned short* V = vt + (size_t)bh * cDK * cT;
  const int d0 = (wave & 3) * 16;
  const int kh2 = wave >> 2;                    // 0: keys 0-511, 1: keys 512-1023
  floatx4 acc = (floatx4){0.f, 0.f, 0.f, 0.f};
  for (int ks = 0; ks < 16; ks++){
    const int j0 = (kh2 * 16 + ks) * 32;
    const short8 vf = ld8(V + (size_t)(d0 + l15) * cT + j0 + lq * 8);
    const short8 af = ld8(pbuf + l15 * PBS + j0 + lq * 8);
    acc = MFMA16(af, vf, acc);
  }
  // combine halves via 4 KiB LDS scratch past the pbuf overlay (byte 40960)
  float* red4 = sc + 10240;
  if (kh2 == 1) *(floatx4*)(red4 + ((wave & 3) * 256 + lane * 4)) = acc;
  bar_lds();
  if (kh2 == 0){
    acc += *(const floatx4*)(red4 + ((wave & 3) * 256 + lane * 4));
    #pragma unroll
    for (int r = 0; r < 4; r++){
      const int i = lq * 4 + r;
      out_h[((size_t)b * cT + q0 + i) * cD + h * cDK + d0 + l15] = f2bf(acc[r]);
    }
  }
}

// ---------------- host launcher ----------------
extern "C" void kernel_launch(void* const* d_in, const int* in_sizes, int n_in,
                              void* d_out, int out_size, void* d_ws, size_t ws_size,
                              hipStream_t stream)
{
  const float* q    = (const float*)d_in[0];
  const float* k    = (const float*)d_in[1];
  const float* v    = (const float*)d_in[2];
  const float* pe   = (const float*)d_in[3];
  const int*   mask = (const int*)d_in[4];
  const float* lnqg = (const float*)d_in[5];
  const float* lnqb = (const float*)d_in[6];
  const float* lnkg = (const float*)d_in[7];
  const float* lnkb = (const float*)d_in[8];
  const float* lnvg = (const float*)d_in[9];
  const float* lnvb = (const float*)d_in[10];
  const float* wq   = (const float*)d_in[11];
  const float* wk   = (const float*)d_in[12];
  const float* wv   = (const float*)d_in[13];
  const float* wpos = (const float*)d_in[14];
  const float* wfc  = (const float*)d_in[15];
  const float* pbu  = (const float*)d_in[16];
  const float* pbv  = (const float*)d_in[17];

  float* out_f  = (float*)d_out;                       // [8,1024,512] f32
  float* attn_f = out_f + (size_t)8 * 1024 * 512;      // [8,8,1024,1024] f32, 268 MB

  // --- scratch dead before attn_kernel lives inside the attn output region ---
  unsigned char* scr = (unsigned char*)attn_f;
  size_t soff = 0;
  auto salloc = [&](size_t bytes){ void* p = scr + soff; soff += (bytes + 255) & ~(size_t)255; return p; };
  unsigned short* qn   = (unsigned short*)salloc((size_t)8192 * 512 * 2);  // qn,kn,vn consecutive
  unsigned short* kn   = (unsigned short*)salloc((size_t)8192 * 512 * 2);
  unsigned short* vn   = (unsigned short*)salloc((size_t)8192 * 512 * 2);
  unsigned short* pe_b = (unsigned short*)salloc((size_t)2047 * 512 * 2);
  (void)kn; (void)vn;

  // --- workspace: buffers that live across / after attn_kernel (~46 MB) ---
  unsigned char* ws = (unsigned char*)d_ws;
  size_t off = 0;
  auto alloc = [&](size_t bytes){ void* p = ws + off; off += (bytes + 255) & ~(size_t)255; return p; };
  unsigned short* w5_b = (unsigned short*)alloc(5 * 512 * 512 * 2);        // wq,wk,wv,wpos,wfc
  unsigned short* qhb  = (unsigned short*)alloc((size_t)8192 * 512 * 2);   // qhb,khb,vhb consecutive
  unsigned short* khb  = (unsigned short*)alloc((size_t)8192 * 512 * 2);
  unsigned short* vhb  = (unsigned short*)alloc((size_t)8192 * 512 * 2);
  unsigned short* vtb  = (unsigned short*)alloc((size_t)8192 * 512 * 2);   // [B,H,64,T]
  unsigned short* ppb  = (unsigned short*)alloc((size_t)8 * 2047 * 64 * 2);// [H,P,64]
  float*          ub   = (float*)alloc((size_t)8 * 8 * 1024 * 4);          // [B,H,T]
  float*          vbias= (float*)alloc((size_t)8 * 2047 * 4);              // [H,P]
  unsigned short* ohb  = (unsigned short*)alloc((size_t)8192 * 512 * 2);   // [B,T,512]
  unsigned int*   bmask= (unsigned int*)alloc((size_t)8192 * 32 * 4);      // [B,T,32]
  (void)ws_size; (void)n_in; (void)in_sizes; (void)out_size;

  Ptr5 c5; c5.p[0] = wq; c5.p[1] = wk; c5.p[2] = wv; c5.p[3] = wpos; c5.p[4] = wfc;
  cast5_kernel<<<5120, 256, 0, stream>>>(c5, w5_b);
  cast1_kernel<<<4094, 256, 0, stream>>>(pe, pe_b, 2047 * 512);
  maskbits_kernel<<<2048, 256, 0, stream>>>(mask, bmask);

  LN3 l3;
  l3.x[0] = q; l3.x[1] = k; l3.x[2] = v;
  l3.g[0] = lnqg; l3.g[1] = lnkg; l3.g[2] = lnvg;
  l3.b[0] = lnqb; l3.b[1] = lnkb; l3.b[2] = lnvb;
  l3.y[0] = qn; l3.y[1] = kn; l3.y[2] = vn;
  ln3_kernel<<<dim3(8192, 3), 256, 0, stream>>>(l3);

  // fused QKV projections (z=0:q scaled by 1/8, z=1:k, z=2:v)
  gemm512_kernel<<<dim3(4, 64, 3), 256, 0, stream>>>(qn, w5_b, 8192, 0, 0.125f,
                                                     qhb, nullptr, nullptr);
  gemm512_kernel<<<dim3(4, 16, 1), 256, 0, stream>>>(pe_b, w5_b + 3 * 262144, 2047, 1, 1.0f,
                                                     ppb, nullptr, nullptr);

  transpose_v_kernel<<<dim3(64, 16), 256, 0, stream>>>(vhb, vtb);

  dot_bias_kernel<<<16384, 256, 0, stream>>>(khb, pbu, ub, 65536, 1024, 0.125f);
  dot_bias_kernel<<<4094, 256, 0, stream>>>(ppb, pbv, vbias, 16376, 2047, 0.125f);

  attn_kernel<<<dim3(64, 64), 512, 0, stream>>>(qhb, khb, vtb, ppb, ub, vbias,
                                                bmask, attn_f, ohb);

  gemm512_kernel<<<dim3(4, 64, 1), 256, 0, stream>>>(ohb, w5_b + 4 * 262144, 8192, 2, 1.0f,
                                                     nullptr, out_f, q);
}

// Round 4
// 686.519 us; speedup vs baseline: 1.3160x; 1.0518x over previous
//
#include <hip/hip_runtime.h>

constexpr int cT  = 1024;
constexpr int cD  = 512;
constexpr int cDK = 64;
constexpr int cP  = 2047;
constexpr int PBS = 1040;   // bf16 prob-buffer row stride (pad 16 -> +8 banks/row)

typedef __attribute__((ext_vector_type(8))) short short8;
typedef __attribute__((ext_vector_type(4))) float floatx4;

#define MFMA16(a,b,c) __builtin_amdgcn_mfma_f32_16x16x32_bf16((a),(b),(c),0,0,0)
// swizzle keyed on i>>2 (varies across lanes within a store), not i&3 (constant)
// XORs only bit 3 of j -> 4-aligned j-groups stay contiguous (b128-safe)
#define SWZ(i,j) ((j) ^ ((((i) >> 2) & 3) << 3))

// barrier that does NOT drain vmcnt: LDS ordering only.
__device__ __forceinline__ void bar_lds(){
  asm volatile("s_waitcnt lgkmcnt(0)\n\ts_barrier" ::: "memory");
}

__device__ __forceinline__ unsigned short f2bf(float f){
  union { float f; unsigned int u; } x; x.f = f;
  unsigned int r = x.u + 0x7fffu + ((x.u >> 16) & 1u);   // RNE
  return (unsigned short)(r >> 16);
}
__device__ __forceinline__ float bf2f(unsigned short h){
  union { unsigned int u; float f; } x; x.u = ((unsigned int)h) << 16;
  return x.f;
}
__device__ __forceinline__ short8 ld8(const unsigned short* p){
  return *(const short8*)p;
}

// ---------------- LayerNorm x3 + cast to bf16 ----------------
struct LN3 { const float* x[3]; const float* g[3]; const float* b[3]; unsigned short* y[3]; };
__global__ void __launch_bounds__(256) ln3_kernel(LN3 a)
{
  __shared__ float red[8];
  const int z = blockIdx.y, r = blockIdx.x;
  const float* x = a.x[z]; const float* g = a.g[z]; const float* b = a.b[z];
  unsigned short* y = a.y[z];
  const float2 v = ((const float2*)(x + (size_t)r * cD))[threadIdx.x];
  float s = v.x + v.y, sq = v.x * v.x + v.y * v.y;
  #pragma unroll
  for (int o = 32; o; o >>= 1){ s += __shfl_xor(s, o); sq += __shfl_xor(sq, o); }
  const int w = threadIdx.x >> 6;
  if ((threadIdx.x & 63) == 0){ red[w * 2] = s; red[w * 2 + 1] = sq; }
  __syncthreads();
  s  = red[0] + red[2] + red[4] + red[6];
  sq = red[1] + red[3] + red[5] + red[7];
  const float mu  = s * (1.0f / cD);
  const float var = sq * (1.0f / cD) - mu * mu;
  const float rs  = rsqrtf(var + 1e-5f);
  const int c = threadIdx.x * 2;
  const unsigned int o0 = f2bf((v.x - mu) * rs * g[c]     + b[c]);
  const unsigned int o1 = f2bf((v.y - mu) * rs * g[c + 1] + b[c + 1]);
  ((unsigned int*)(y + (size_t)r * cD))[threadIdx.x] = o0 | (o1 << 16);
}

// ---------------- f32 -> bf16 casts ----------------
struct Ptr5 { const float* p[5]; };
__global__ void __launch_bounds__(256) cast5_kernel(Ptr5 s, unsigned short* __restrict__ d){
  const int idx = blockIdx.x * 256 + threadIdx.x;          // 5 * 262144 total
  const int seg = idx >> 18, off = idx & 262143;
  d[idx] = f2bf(s.p[seg][off]);
}
__global__ void __launch_bounds__(256) cast1_kernel(const float* __restrict__ s,
    unsigned short* __restrict__ d, int n){
  const int idx = blockIdx.x * 256 + threadIdx.x;
  if (idx < n) d[idx] = f2bf(s[idx]);
}

// ---------------- mask -> bitmask: bm[(b*T+t)*32 + w] bit (j&31) = mask!=0 ----------------
__global__ void __launch_bounds__(256) maskbits_kernel(
    const int* __restrict__ mask, unsigned int* __restrict__ bm)
{
  const int row = blockIdx.x * 4 + (threadIdx.x >> 6);
  const int lane = threadIdx.x & 63;
  #pragma unroll
  for (int ii = 0; ii < 16; ii++){
    const int m = mask[(size_t)row * cT + ii * 64 + lane];
    const unsigned long long bal = __ballot(m != 0);
    if (lane == 0)       bm[row * 32 + ii * 2]     = (unsigned int)bal;
    else if (lane == 32) bm[row * 32 + ii * 2 + 1] = (unsigned int)(bal >> 32);
  }
}

// ---------------- GEMM: Y[r][o] = scale * sum_k A[r][k] * W[o][k]; K=N=512 ------------
// unroll 2: two K-steps of loads visible to the scheduler; launch_bounds(256,4)
// caps VGPR at 128 so pipelining never costs occupancy (16 waves/CU).
__global__ void __launch_bounds__(256, 4) gemm512_kernel(
    const unsigned short* __restrict__ A0, const unsigned short* __restrict__ W0,
    int M, int mode, float scaleA, unsigned short* __restrict__ outb,
    float* __restrict__ outf, const float* __restrict__ residual)
{
  const int z = blockIdx.z;
  const unsigned short* A = A0 + (size_t)z * 4194304;
  const unsigned short* W = W0 + (size_t)z * 262144;
  unsigned short* outz = outb ? outb + (size_t)z * 4194304 : outb;
  const float sA = (z == 0) ? scaleA : 1.0f;
  const int n0 = blockIdx.x * 128, m0 = blockIdx.y * 128;
  const int wave = threadIdx.x >> 6, lane = threadIdx.x & 63;
  const int wr = wave >> 1, wc = wave & 1;
  const int l15 = lane & 15, lq = lane >> 4;
  const int mb = m0 + wr * 64, nb = n0 + wc * 64;
  floatx4 acc[4][4];
  #pragma unroll
  for (int i = 0; i < 4; i++)
    #pragma unroll
    for (int j = 0; j < 4; j++) acc[i][j] = (floatx4){0.f, 0.f, 0.f, 0.f};
  #pragma unroll 2
  for (int k0 = 0; k0 < 512; k0 += 32){
    short8 af[4], bf[4];
    #pragma unroll
    for (int i = 0; i < 4; i++){
      int row = mb + i * 16 + l15; if (row >= M) row = M - 1;
      af[i] = ld8(A + (size_t)row * 512 + k0 + lq * 8);
      const int col = nb + i * 16 + l15;
      bf[i] = ld8(W + (size_t)col * 512 + k0 + lq * 8);
    }
    #pragma unroll
    for (int i = 0; i < 4; i++)
      #pragma unroll
      for (int j = 0; j < 4; j++)
        acc[i][j] = MFMA16(af[i], bf[j], acc[i][j]);
  }
  #pragma unroll
  for (int i = 0; i < 4; i++){
    #pragma unroll
    for (int j = 0; j < 4; j++){
      #pragma unroll
      for (int r = 0; r < 4; r++){
        const int row = mb + i * 16 + lq * 4 + r;
        const int col = nb + j * 16 + l15;
        if (row >= M) continue;
        const float val = acc[i][j][r] * sA;
        if (mode == 0){
          const int bb = row >> 10, t = row & 1023, h = col >> 6, d = col & 63;
          outz[(((size_t)(bb * 8 + h) * 1024 + t) << 6) + d] = f2bf(val);
        } else if (mode == 1){
          const int h = col >> 6, d = col & 63;
          outz[(((size_t)h * 2047 + row) << 6) + d] = f2bf(val);
        } else {
          const size_t idx = (size_t)row * 512 + col;
          outf[idx] = val + residual[idx];
        }
      }
    }
  }
}

// ---------------- V transpose: [BH,T,64] -> [BH,64,T] ----------------
__global__ void __launch_bounds__(256) transpose_v_kernel(
    const unsigned short* __restrict__ vh, unsigned short* __restrict__ vt)
{
  __shared__ unsigned short tile[64][65];
  const int bh = blockIdx.x, t0 = blockIdx.y * 64;
  const unsigned short* src = vh + ((size_t)bh * cT + t0) * cDK;
  #pragma unroll
  for (int i = 0; i < 16; i++){
    const int idx = threadIdx.x + i * 256;
    tile[idx >> 6][idx & 63] = src[idx];
  }
  __syncthreads();
  unsigned short* dst = vt + (size_t)bh * cDK * cT + t0;
  #pragma unroll
  for (int i = 0; i < 16; i++){
    const int idx = threadIdx.x + i * 256;
    const int d = idx >> 6, t = idx & 63;
    dst[(size_t)d * cT + t] = tile[t][d];
  }
}

// ---------------- per-key bias: out[row] = scale * dot64(bias[h], X[row]) ----------------
__global__ void __launch_bounds__(256) dot_bias_kernel(
    const unsigned short* __restrict__ X, const float* __restrict__ bias,
    float* __restrict__ out, int rows, int hdiv, float scale)
{
  const int row = blockIdx.x * 4 + (threadIdx.x >> 6);
  const int lane = threadIdx.x & 63;
  if (row >= rows) return;
  const int h = (row / hdiv) & 7;
  float s = bf2f(X[(size_t)row * 64 + lane]) * bias[h * 64 + lane];
  #pragma unroll
  for (int o = 32; o; o >>= 1) s += __shfl_xor(s, o);
  if (lane == 0) out[row] = s * scale;
}

// ---------------- fused relpos attention: block = (b,h, 16 q-rows), 8 waves ----------------
// scale (1/8) pre-folded into qh / ubias / vbias.
// 512 threads, 64 KiB LDS -> 2 blocks/CU, 16 waves/CU.
// Phase 3 uses contiguous-4 lane ownership (j = 4*lane + 256*ii):
//   sc reads   : 4x ds_read_b128 (lane stride 16B -> conflict-free)
//   NT stores  : 4x dwordx4, one wave instr = 1024 contiguous B = 16 FULL lines
//   pbuf writes: 4x b64 contiguous
// (round-2 lesson: lane-owned 64B block -> partial-line NT writes -> 2.7x
//  write amplification; this pattern is line-complete.)
__global__ void __launch_bounds__(512, 4) attn_kernel(
    const unsigned short* __restrict__ qh, const unsigned short* __restrict__ kh,
    const unsigned short* __restrict__ vt, const unsigned short* __restrict__ pproj,
    const float* __restrict__ ubias, const float* __restrict__ vbias,
    const unsigned int* __restrict__ bm, float* __restrict__ attn_out,
    unsigned short* __restrict__ out_h)
{
  __shared__ float sc[16 * cT];                 // 64 KiB f32 scores
  unsigned short* pbuf = (unsigned short*)sc;   // bf16 [16][PBS] overlay (33,248 B), used after
  const int bh = blockIdx.x, b = bh >> 3, h = bh & 7;
  const int q0 = blockIdx.y * 16;
  const int wave = threadIdx.x >> 6, lane = threadIdx.x & 63;
  const int l15 = lane & 15, lq = lane >> 4;
  const unsigned short* Q  = qh + (size_t)bh * cT * cDK;
  const unsigned short* Kp = kh + (size_t)bh * cT * cDK;
  const unsigned short* Pt = pproj + (size_t)h * cP * cDK;
  const float* ub = ubias + (size_t)bh * cT;
  const float* vb = vbias + (size_t)h * cP;

  const short8 qf0 = ld8(Q + (size_t)(q0 + l15) * cDK + lq * 8);
  const short8 qf1 = ld8(Q + (size_t)(q0 + l15) * cDK + 32 + lq * 8);

  // ---- phase 1: ac = Q K^T + ub + vb -> LDS (2-way banks via SWZ) ----
  #pragma unroll
  for (int t = 0; t < 8; t++){
    const int jt = wave + t * 8;
    const short8 kf0 = ld8(Kp + (size_t)(jt * 16 + l15) * cDK + lq * 8);
    const short8 kf1 = ld8(Kp + (size_t)(jt * 16 + l15) * cDK + 32 + lq * 8);
    floatx4 acc = (floatx4){0.f, 0.f, 0.f, 0.f};
    acc = MFMA16(qf0, kf0, acc);
    acc = MFMA16(qf1, kf1, acc);
    const int jb = jt * 16 + l15;
    const float ubv = ub[jb];
    #pragma unroll
    for (int r = 0; r < 4; r++){
      const int i = lq * 4 + r;
      sc[i * cT + (jb ^ (lq << 3))] = acc[r] + ubv + vb[jb + (cT - 1) - (q0 + i)];
    }
  }
  bar_lds();

  // ---- phase 2: bd window GEMM, diagonal scatter-add  j = c - 15 + i ----
  const int w0 = (cT - 1) - q0 - 15;
  #pragma unroll
  for (int t = 0; t < 8; t++){
    const int ct = wave + t * 8;                // 0..63
    const int c = ct * 16 + l15;
    int prow = w0 + c; if (prow > cP - 1) prow = cP - 1;
    const short8 pf0 = ld8(Pt + (size_t)prow * cDK + lq * 8);
    const short8 pf1 = ld8(Pt + (size_t)prow * cDK + 32 + lq * 8);
    floatx4 acc = (floatx4){0.f, 0.f, 0.f, 0.f};
    acc = MFMA16(qf0, pf0, acc);
    acc = MFMA16(qf1, pf1, acc);
    #pragma unroll
    for (int r = 0; r < 4; r++){
      const int i = lq * 4 + r;
      const int j = c - 15 + i;
      if (j >= 0 && j < cT) sc[i * cT + SWZ(i, j)] += acc[r];
    }
  }
  if (wave == 0){                               // tail column-tile ct=64
    const int c = 1024 + l15;
    int prow = w0 + c; if (prow > cP - 1) prow = cP - 1;
    const short8 pf0 = ld8(Pt + (size_t)prow * cDK + lq * 8);
    const short8 pf1 = ld8(Pt + (size_t)prow * cDK + 32 + lq * 8);
    floatx4 acc = (floatx4){0.f, 0.f, 0.f, 0.f};
    acc = MFMA16(qf0, pf0, acc);
    acc = MFMA16(qf1, pf1, acc);
    #pragma unroll
    for (int r = 0; r < 4; r++){
      const int i = lq * 4 + r;
      const int j = c - 15 + i;
      if (j >= 0 && j < cT) sc[i * cT + SWZ(i, j)] += acc[r];
    }
  }
  bar_lds();

  // ---- V prefetch (first half of phase-4 fragments; ~32 VGPR, hidden under phase 3)
  const unsigned short* V = vt + (size_t)bh * cDK * cT;
  const int d0 = (wave & 3) * 16;
  const int kh2 = wave >> 2;                    // 0: keys 0-511, 1: keys 512-1023
  short8 vfr[8];
  #pragma unroll
  for (int ks = 0; ks < 8; ks++){
    const int j0v = (kh2 * 16 + ks) * 32;
    vfr[ks] = ld8(V + (size_t)(d0 + l15) * cT + j0v + lq * 8);
  }

  // ---- phase 3: masked softmax, 2 passes (read | barrier | write), 8 rows/pass ----
  // contiguous-4 ownership: lane owns j in {4*lane+256*ii | ii=0..3}.
  // pbuf overlay safety identical to before: pass-p writes touch only sc rows
  // already fully consumed before pass p's barrier.
  for (int p = 0; p < 2; p++){
    const int i = p * 8 + wave;
    const int qrow = q0 + i;
    const unsigned int* bmr = bm + ((size_t)b * cT + qrow) * 32;
    const int xr = ((i >> 2) & 3) << 3;
    float vals[16];
    float mx = -INFINITY;
    #pragma unroll
    for (int ii = 0; ii < 4; ii++){
      const int j0 = lane * 4 + ii * 256;
      const unsigned int mw = bmr[(lane >> 3) + ii * 8] >> (4 * (lane & 7));
      const floatx4 sv = *(const floatx4*)&sc[i * cT + (j0 ^ xr)];
      #pragma unroll
      for (int tt = 0; tt < 4; tt++){
        float s = sv[tt];
        if (((mw >> tt) & 1u) == 0u) s = -INFINITY;
        vals[ii * 4 + tt] = s;
        mx = fmaxf(mx, s);
      }
    }
    #pragma unroll
    for (int o = 32; o; o >>= 1) mx = fmaxf(mx, __shfl_xor(mx, o));
    float sum = 0.f;
    #pragma unroll
    for (int ii = 0; ii < 16; ii++){
      const float e = (vals[ii] == -INFINITY) ? 0.f : __expf(vals[ii] - mx);
      vals[ii] = e; sum += e;
    }
    #pragma unroll
    for (int o = 32; o; o >>= 1) sum += __shfl_xor(sum, o);
    const float ri = sum > 0.f ? 1.f / sum : 0.f;
    bar_lds();            // all sc reads of this pass's rows complete (lgkm only)
    float* arow = attn_out + ((size_t)bh * cT + qrow) * cT;
    unsigned short* prow_lds = pbuf + (size_t)i * PBS;
    #pragma unroll
    for (int ii = 0; ii < 4; ii++){
      const int j0 = lane * 4 + ii * 256;
      floatx4 pv;
      #pragma unroll
      for (int tt = 0; tt < 4; tt++) pv[tt] = vals[ii * 4 + tt] * ri;
      __builtin_nontemporal_store(pv, (floatx4*)(arow + j0));
      const unsigned int wlo = (unsigned int)f2bf(pv[0]) | ((unsigned int)f2bf(pv[1]) << 16);
      const unsigned int whi = (unsigned int)f2bf(pv[2]) | ((unsigned int)f2bf(pv[3]) << 16);
      *(unsigned long long*)(prow_lds + j0) =
          (unsigned long long)wlo | ((unsigned long long)whi << 32);
    }
  }
  bar_lds();

  // ---- phase 4: O = P V; first 8 key-slices from prefetched regs ----
  floatx4 acc = (floatx4){0.f, 0.f, 0.f, 0.f};
  #pragma unroll
  for (int ks = 0; ks < 8; ks++){
    const int j0 = (kh2 * 16 + ks) * 32;
    const short8 af = ld8(pbuf + l15 * PBS + j0 + lq * 8);
    acc = MFMA16(af, vfr[ks], acc);
  }
  #pragma unroll
  for (int ks = 8; ks < 16; ks++){
    const int j0 = (kh2 * 16 + ks) * 32;
    const short8 vf = ld8(V + (size_t)(d0 + l15) * cT + j0 + lq * 8);
    const short8 af = ld8(pbuf + l15 * PBS + j0 + lq * 8);
    acc = MFMA16(af, vf, acc);
  }
  // combine halves via 4 KiB LDS scratch past the pbuf overlay (byte 40960)
  float* red4 = sc + 10240;
  if (kh2 == 1) *(floatx4*)(red4 + ((wave & 3) * 256 + lane * 4)) = acc;
  bar_lds();
  if (kh2 == 0){
    acc += *(const floatx4*)(red4 + ((wave & 3) * 256 + lane * 4));
    #pragma unroll
    for (int r = 0; r < 4; r++){
      const int i = lq * 4 + r;
      out_h[((size_t)b * cT + q0 + i) * cD + h * cDK + d0 + l15] = f2bf(acc[r]);
    }
  }
}

// ---------------- host launcher ----------------
extern "C" void kernel_launch(void* const* d_in, const int* in_sizes, int n_in,
                              void* d_out, int out_size, void* d_ws, size_t ws_size,
                              hipStream_t stream)
{
  const float* q    = (const float*)d_in[0];
  const float* k    = (const float*)d_in[1];
  const float* v    = (const float*)d_in[2];
  const float* pe   = (const float*)d_in[3];
  const int*   mask = (const int*)d_in[4];
  const float* lnqg = (const float*)d_in[5];
  const float* lnqb = (const float*)d_in[6];
  const float* lnkg = (const float*)d_in[7];
  const float* lnkb = (const float*)d_in[8];
  const float* lnvg = (const float*)d_in[9];
  const float* lnvb = (const float*)d_in[10];
  const float* wq   = (const float*)d_in[11];
  const float* wk   = (const float*)d_in[12];
  const float* wv   = (const float*)d_in[13];
  const float* wpos = (const float*)d_in[14];
  const float* wfc  = (const float*)d_in[15];
  const float* pbu  = (const float*)d_in[16];
  const float* pbv  = (const float*)d_in[17];

  float* out_f  = (float*)d_out;                       // [8,1024,512] f32
  float* attn_f = out_f + (size_t)8 * 1024 * 512;      // [8,8,1024,1024] f32, 268 MB

  // --- scratch dead before attn_kernel lives inside the attn output region ---
  unsigned char* scr = (unsigned char*)attn_f;
  size_t soff = 0;
  auto salloc = [&](size_t bytes){ void* p = scr + soff; soff += (bytes + 255) & ~(size_t)255; return p; };
  unsigned short* qn   = (unsigned short*)salloc((size_t)8192 * 512 * 2);  // qn,kn,vn consecutive
  unsigned short* kn   = (unsigned short*)salloc((size_t)8192 * 512 * 2);
  unsigned short* vn   = (unsigned short*)salloc((size_t)8192 * 512 * 2);
  unsigned short* pe_b = (unsigned short*)salloc((size_t)2047 * 512 * 2);
  (void)kn; (void)vn;

  // --- workspace: buffers that live across / after attn_kernel (~46 MB) ---
  unsigned char* ws = (unsigned char*)d_ws;
  size_t off = 0;
  auto alloc = [&](size_t bytes){ void* p = ws + off; off += (bytes + 255) & ~(size_t)255; return p; };
  unsigned short* w5_b = (unsigned short*)alloc(5 * 512 * 512 * 2);        // wq,wk,wv,wpos,wfc
  unsigned short* qhb  = (unsigned short*)alloc((size_t)8192 * 512 * 2);   // qhb,khb,vhb consecutive
  unsigned short* khb  = (unsigned short*)alloc((size_t)8192 * 512 * 2);
  unsigned short* vhb  = (unsigned short*)alloc((size_t)8192 * 512 * 2);
  unsigned short* vtb  = (unsigned short*)alloc((size_t)8192 * 512 * 2);   // [B,H,64,T]
  unsigned short* ppb  = (unsigned short*)alloc((size_t)8 * 2047 * 64 * 2);// [H,P,64]
  float*          ub   = (float*)alloc((size_t)8 * 8 * 1024 * 4);          // [B,H,T]
  float*          vbias= (float*)alloc((size_t)8 * 2047 * 4);              // [H,P]
  unsigned short* ohb  = (unsigned short*)alloc((size_t)8192 * 512 * 2);   // [B,T,512]
  unsigned int*   bmask= (unsigned int*)alloc((size_t)8192 * 32 * 4);      // [B,T,32]
  (void)ws_size; (void)n_in; (void)in_sizes; (void)out_size;

  Ptr5 c5; c5.p[0] = wq; c5.p[1] = wk; c5.p[2] = wv; c5.p[3] = wpos; c5.p[4] = wfc;
  cast5_kernel<<<5120, 256, 0, stream>>>(c5, w5_b);
  cast1_kernel<<<4094, 256, 0, stream>>>(pe, pe_b, 2047 * 512);
  maskbits_kernel<<<2048, 256, 0, stream>>>(mask, bmask);

  LN3 l3;
  l3.x[0] = q; l3.x[1] = k; l3.x[2] = v;
  l3.g[0] = lnqg; l3.g[1] = lnkg; l3.g[2] = lnvg;
  l3.b[0] = lnqb; l3.b[1] = lnkb; l3.b[2] = lnvb;
  l3.y[0] = qn; l3.y[1] = kn; l3.y[2] = vn;
  ln3_kernel<<<dim3(8192, 3), 256, 0, stream>>>(l3);

  // fused QKV projections (z=0:q scaled by 1/8, z=1:k, z=2:v)
  gemm512_kernel<<<dim3(4, 64, 3), 256, 0, stream>>>(qn, w5_b, 8192, 0, 0.125f,
                                                     qhb, nullptr, nullptr);
  gemm512_kernel<<<dim3(4, 16, 1), 256, 0, stream>>>(pe_b, w5_b + 3 * 262144, 2047, 1, 1.0f,
                                                     ppb, nullptr, nullptr);

  transpose_v_kernel<<<dim3(64, 16), 256, 0, stream>>>(vhb, vtb);

  dot_bias_kernel<<<16384, 256, 0, stream>>>(khb, pbu, ub, 65536, 1024, 0.125f);
  dot_bias_kernel<<<4094, 256, 0, stream>>>(ppb, pbv, vbias, 16376, 2047, 0.125f);

  attn_kernel<<<dim3(64, 64), 512, 0, stream>>>(qhb, khb, vtb, ppb, ub, vbias,
                                                bmask, attn_f, ohb);

  gemm512_kernel<<<dim3(4, 64, 1), 256, 0, stream>>>(ohb, w5_b + 4 * 262144, 8192, 2, 1.0f,
                                                     nullptr, out_f, q);
}

// Round 5
// 671.539 us; speedup vs baseline: 1.3454x; 1.0223x over previous
//
#include <hip/hip_runtime.h>

constexpr int cT  = 1024;
constexpr int cD  = 512;
constexpr int cDK = 64;
constexpr int cP  = 2047;
constexpr int PBS = 1040;   // bf16 prob-buffer row stride (pad 16 -> +8 banks/row)

typedef __attribute__((ext_vector_type(8))) short short8;
typedef __attribute__((ext_vector_type(4))) float floatx4;

#define MFMA16(a,b,c) __builtin_amdgcn_mfma_f32_16x16x32_bf16((a),(b),(c),0,0,0)
// swizzle keyed on i>>2 (varies across lanes within a store), not i&3 (constant)
// XORs only bit 3 of j -> 4-aligned j-groups stay contiguous (b128-safe)
#define SWZ(i,j) ((j) ^ ((((i) >> 2) & 3) << 3))

// barrier that does NOT drain vmcnt: LDS ordering only.
__device__ __forceinline__ void bar_lds(){
  asm volatile("s_waitcnt lgkmcnt(0)\n\ts_barrier" ::: "memory");
}

__device__ __forceinline__ unsigned short f2bf(float f){
  union { float f; unsigned int u; } x; x.f = f;
  unsigned int r = x.u + 0x7fffu + ((x.u >> 16) & 1u);   // RNE
  return (unsigned short)(r >> 16);
}
__device__ __forceinline__ float bf2f(unsigned short h){
  union { unsigned int u; float f; } x; x.u = ((unsigned int)h) << 16;
  return x.f;
}
__device__ __forceinline__ short8 ld8(const unsigned short* p){
  return *(const short8*)p;
}

// ---------------- LayerNorm x3 + cast to bf16 (float4 loads, 2 rows/block) ----------------
struct LN3 { const float* x[3]; const float* g[3]; const float* b[3]; unsigned short* y[3]; };
__global__ void __launch_bounds__(256) ln3_kernel(LN3 a)
{
  __shared__ float red[8];                      // [half][wave-in-half][s,sq]
  const int z = blockIdx.y;
  const int half = threadIdx.x >> 7;            // 0,1 -> row within block
  const int r = blockIdx.x * 2 + half;
  const int tid = threadIdx.x & 127;            // 128 threads per row, float4 each
  const float* x = a.x[z]; const float* g = a.g[z]; const float* b = a.b[z];
  unsigned short* y = a.y[z];
  const float4 v = ((const float4*)(x + (size_t)r * cD))[tid];
  float s  = v.x + v.y + v.z + v.w;
  float sq = v.x * v.x + v.y * v.y + v.z * v.z + v.w * v.w;
  #pragma unroll
  for (int o = 32; o; o >>= 1){ s += __shfl_xor(s, o); sq += __shfl_xor(sq, o); }
  const int w = (threadIdx.x >> 6) & 1;         // wave within the row-half
  if ((threadIdx.x & 63) == 0){ red[half * 4 + w * 2] = s; red[half * 4 + w * 2 + 1] = sq; }
  __syncthreads();
  s  = red[half * 4]     + red[half * 4 + 2];
  sq = red[half * 4 + 1] + red[half * 4 + 3];
  const float mu  = s * (1.0f / cD);
  const float var = sq * (1.0f / cD) - mu * mu;
  const float rs  = rsqrtf(var + 1e-5f);
  const int c = tid * 4;
  const float4 gv = *(const float4*)(g + c);
  const float4 bv = *(const float4*)(b + c);
  const unsigned int o0 = (unsigned int)f2bf((v.x - mu) * rs * gv.x + bv.x)
                        | ((unsigned int)f2bf((v.y - mu) * rs * gv.y + bv.y) << 16);
  const unsigned int o1 = (unsigned int)f2bf((v.z - mu) * rs * gv.z + bv.z)
                        | ((unsigned int)f2bf((v.w - mu) * rs * gv.w + bv.w) << 16);
  ((uint2*)(y + (size_t)r * cD))[tid] = make_uint2(o0, o1);
}

// ---------------- f32 -> bf16 casts ----------------
struct Ptr5 { const float* p[5]; };
__global__ void __launch_bounds__(256) cast5_kernel(Ptr5 s, unsigned short* __restrict__ d){
  const int idx = blockIdx.x * 256 + threadIdx.x;          // 5 * 262144 total
  const int seg = idx >> 18, off = idx & 262143;
  d[idx] = f2bf(s.p[seg][off]);
}
__global__ void __launch_bounds__(256) cast1_kernel(const float* __restrict__ s,
    unsigned short* __restrict__ d, int n){
  const int idx = blockIdx.x * 256 + threadIdx.x;
  if (idx < n) d[idx] = f2bf(s[idx]);
}

// ---------------- mask -> bitmask: bm[(b*T+t)*32 + w] bit (j&31) = mask!=0 ----------------
__global__ void __launch_bounds__(256) maskbits_kernel(
    const int* __restrict__ mask, unsigned int* __restrict__ bm)
{
  const int row = blockIdx.x * 4 + (threadIdx.x >> 6);
  const int lane = threadIdx.x & 63;
  #pragma unroll
  for (int ii = 0; ii < 16; ii++){
    const int m = mask[(size_t)row * cT + ii * 64 + lane];
    const unsigned long long bal = __ballot(m != 0);
    if (lane == 0)       bm[row * 32 + ii * 2]     = (unsigned int)bal;
    else if (lane == 32) bm[row * 32 + ii * 2 + 1] = (unsigned int)(bal >> 32);
  }
}

// ---------------- GEMM: Y[r][o] = scale * sum_k A[r][k] * W[o][k]; K=N=512 ------------
// mode 0, z==0: adds addq[col] to acc BEFORE scaling (folds pos_bias_u into qh).
__global__ void __launch_bounds__(256, 4) gemm512_kernel(
    const unsigned short* __restrict__ A0, const unsigned short* __restrict__ W0,
    int M, int mode, float scaleA, unsigned short* __restrict__ outb,
    float* __restrict__ outf, const float* __restrict__ residual,
    const float* __restrict__ addq)
{
  const int z = blockIdx.z;
  const unsigned short* A = A0 + (size_t)z * 4194304;
  const unsigned short* W = W0 + (size_t)z * 262144;
  unsigned short* outz = outb ? outb + (size_t)z * 4194304 : outb;
  const float sA = (z == 0) ? scaleA : 1.0f;
  const int n0 = blockIdx.x * 128, m0 = blockIdx.y * 128;
  const int wave = threadIdx.x >> 6, lane = threadIdx.x & 63;
  const int wr = wave >> 1, wc = wave & 1;
  const int l15 = lane & 15, lq = lane >> 4;
  const int mb = m0 + wr * 64, nb = n0 + wc * 64;
  floatx4 acc[4][4];
  #pragma unroll
  for (int i = 0; i < 4; i++)
    #pragma unroll
    for (int j = 0; j < 4; j++) acc[i][j] = (floatx4){0.f, 0.f, 0.f, 0.f};
  #pragma unroll 2
  for (int k0 = 0; k0 < 512; k0 += 32){
    short8 af[4], bf[4];
    #pragma unroll
    for (int i = 0; i < 4; i++){
      int row = mb + i * 16 + l15; if (row >= M) row = M - 1;
      af[i] = ld8(A + (size_t)row * 512 + k0 + lq * 8);
      const int col = nb + i * 16 + l15;
      bf[i] = ld8(W + (size_t)col * 512 + k0 + lq * 8);
    }
    #pragma unroll
    for (int i = 0; i < 4; i++)
      #pragma unroll
      for (int j = 0; j < 4; j++)
        acc[i][j] = MFMA16(af[i], bf[j], acc[i][j]);
  }
  #pragma unroll
  for (int i = 0; i < 4; i++){
    #pragma unroll
    for (int j = 0; j < 4; j++){
      #pragma unroll
      for (int r = 0; r < 4; r++){
        const int row = mb + i * 16 + lq * 4 + r;
        const int col = nb + j * 16 + l15;
        if (row >= M) continue;
        float val = acc[i][j][r];
        if (mode == 0 && z == 0 && addq) val += addq[col];
        val *= sA;
        if (mode == 0){
          const int bb = row >> 10, t = row & 1023, h = col >> 6, d = col & 63;
          outz[(((size_t)(bb * 8 + h) * 1024 + t) << 6) + d] = f2bf(val);
        } else if (mode == 1){
          const int h = col >> 6, d = col & 63;
          outz[(((size_t)h * 2047 + row) << 6) + d] = f2bf(val);
        } else {
          const size_t idx = (size_t)row * 512 + col;
          outf[idx] = val + residual[idx];
        }
      }
    }
  }
}

// ---------------- V transpose: [BH,T,64] -> [BH,64,T] ----------------
__global__ void __launch_bounds__(256) transpose_v_kernel(
    const unsigned short* __restrict__ vh, unsigned short* __restrict__ vt)
{
  __shared__ unsigned short tile[64][65];
  const int bh = blockIdx.x, t0 = blockIdx.y * 64;
  const unsigned short* src = vh + ((size_t)bh * cT + t0) * cDK;
  #pragma unroll
  for (int i = 0; i < 16; i++){
    const int idx = threadIdx.x + i * 256;
    tile[idx >> 6][idx & 63] = src[idx];
  }
  __syncthreads();
  unsigned short* dst = vt + (size_t)bh * cDK * cT + t0;
  #pragma unroll
  for (int i = 0; i < 16; i++){
    const int idx = threadIdx.x + i * 256;
    const int d = idx >> 6, t = idx & 63;
    dst[(size_t)d * cT + t] = tile[t][d];
  }
}

// ---------------- per-key bias: out[row] = scale * dot64(bias-bias2, X[row]) ----------------
__global__ void __launch_bounds__(256) dot_bias_kernel(
    const unsigned short* __restrict__ X, const float* __restrict__ bias,
    const float* __restrict__ bias2, float* __restrict__ out,
    int rows, int hdiv, float scale)
{
  const int row = blockIdx.x * 4 + (threadIdx.x >> 6);
  const int lane = threadIdx.x & 63;
  if (row >= rows) return;
  const int h = (row / hdiv) & 7;
  float bv = bias[h * 64 + lane];
  if (bias2) bv -= bias2[h * 64 + lane];
  float s = bf2f(X[(size_t)row * 64 + lane]) * bv;
  #pragma unroll
  for (int o = 32; o; o >>= 1) s += __shfl_xor(s, o);
  if (lane == 0) out[row] = s * scale;
}

// ---------------- fused relpos attention: block = (b,h, 16 q-rows), 8 waves ----------------
// qh already contains (q@Wq^T + pos_bias_u) * 1/8 -> no ub term anywhere.
// bd bias (pos_bias_v - pos_bias_u)-projected = vb[prow], prow = w0 + c is
// register-index-independent -> single load folded into phase-2 scatter-add.
// Phases 1/2 stage ALL fragment loads (64 VGPR) before MFMAs: one L2
// round-trip per phase instead of eight.
__global__ void __launch_bounds__(512, 4) attn_kernel(
    const unsigned short* __restrict__ qh, const unsigned short* __restrict__ kh,
    const unsigned short* __restrict__ vt, const unsigned short* __restrict__ pproj,
    const float* __restrict__ vbias, const unsigned int* __restrict__ bm,
    float* __restrict__ attn_out, unsigned short* __restrict__ out_h)
{
  __shared__ float sc[16 * cT];                 // 64 KiB f32 scores
  unsigned short* pbuf = (unsigned short*)sc;   // bf16 [16][PBS] overlay (33,248 B), used after
  const int bh = blockIdx.x, b = bh >> 3, h = bh & 7;
  const int q0 = blockIdx.y * 16;
  const int wave = threadIdx.x >> 6, lane = threadIdx.x & 63;
  const int l15 = lane & 15, lq = lane >> 4;
  const unsigned short* Q  = qh + (size_t)bh * cT * cDK;
  const unsigned short* Kp = kh + (size_t)bh * cT * cDK;
  const unsigned short* Pt = pproj + (size_t)h * cP * cDK;
  const float* vb = vbias + (size_t)h * cP;

  const short8 qf0 = ld8(Q + (size_t)(q0 + l15) * cDK + lq * 8);
  const short8 qf1 = ld8(Q + (size_t)(q0 + l15) * cDK + 32 + lq * 8);

  // ---- phase 1: ac = Q K^T -> LDS (2-way banks via SWZ); staged loads ----
  {
    short8 k0a[8], k1a[8];
    #pragma unroll
    for (int t = 0; t < 8; t++){
      const int jt = wave + t * 8;
      k0a[t] = ld8(Kp + (size_t)(jt * 16 + l15) * cDK + lq * 8);
      k1a[t] = ld8(Kp + (size_t)(jt * 16 + l15) * cDK + 32 + lq * 8);
    }
    #pragma unroll
    for (int t = 0; t < 8; t++){
      const int jt = wave + t * 8;
      floatx4 acc = (floatx4){0.f, 0.f, 0.f, 0.f};
      acc = MFMA16(qf0, k0a[t], acc);
      acc = MFMA16(qf1, k1a[t], acc);
      const int jb = jt * 16 + l15;
      #pragma unroll
      for (int r = 0; r < 4; r++){
        const int i = lq * 4 + r;
        sc[i * cT + (jb ^ (lq << 3))] = acc[r];
      }
    }
  }
  bar_lds();

  // ---- phase 2: bd window GEMM + vb bias, diagonal scatter-add  j = c - 15 + i ----
  const int w0 = (cT - 1) - q0 - 15;
  {
    short8 p0a[8], p1a[8];
    float vba[8];
    #pragma unroll
    for (int t = 0; t < 8; t++){
      const int c = (wave + t * 8) * 16 + l15;
      int prow = w0 + c; if (prow > cP - 1) prow = cP - 1;
      p0a[t] = ld8(Pt + (size_t)prow * cDK + lq * 8);
      p1a[t] = ld8(Pt + (size_t)prow * cDK + 32 + lq * 8);
      vba[t] = vb[prow];
    }
    #pragma unroll
    for (int t = 0; t < 8; t++){
      const int c = (wave + t * 8) * 16 + l15;
      floatx4 acc = (floatx4){0.f, 0.f, 0.f, 0.f};
      acc = MFMA16(qf0, p0a[t], acc);
      acc = MFMA16(qf1, p1a[t], acc);
      #pragma unroll
      for (int r = 0; r < 4; r++){
        const int i = lq * 4 + r;
        const int j = c - 15 + i;
        if (j >= 0 && j < cT) sc[i * cT + SWZ(i, j)] += acc[r] + vba[t];
      }
    }
  }
  if (wave == 0){                               // tail column-tile ct=64
    const int c = 1024 + l15;
    int prow = w0 + c; if (prow > cP - 1) prow = cP - 1;
    const short8 pf0 = ld8(Pt + (size_t)prow * cDK + lq * 8);
    const short8 pf1 = ld8(Pt + (size_t)prow * cDK + 32 + lq * 8);
    const float vbv = vb[prow];
    floatx4 acc = (floatx4){0.f, 0.f, 0.f, 0.f};
    acc = MFMA16(qf0, pf0, acc);
    acc = MFMA16(qf1, pf1, acc);
    #pragma unroll
    for (int r = 0; r < 4; r++){
      const int i = lq * 4 + r;
      const int j = c - 15 + i;
      if (j >= 0 && j < cT) sc[i * cT + SWZ(i, j)] += acc[r] + vbv;
    }
  }
  bar_lds();

  // ---- V prefetch: first 8 of 16 phase-4 fragments (32 VGPR) ----
  const unsigned short* V = vt + (size_t)bh * cDK * cT;
  const int d0 = (wave & 3) * 16;
  const int kh2 = wave >> 2;                    // 0: keys 0-511, 1: keys 512-1023
  short8 vfr[8], vfb[8];
  #pragma unroll
  for (int ks = 0; ks < 8; ks++){
    const int j0v = (kh2 * 16 + ks) * 32;
    vfr[ks] = ld8(V + (size_t)(d0 + l15) * cT + j0v + lq * 8);
  }

  // ---- phase 3: masked softmax, 2 passes (read | barrier | write), 8 rows/pass ----
  // contiguous-4 ownership: lane owns j in {4*lane+256*ii | ii=0..3}.
  // pbuf overlay safety: pass-p writes touch only sc rows already fully
  // consumed before pass p's barrier (same invariant as prior rounds).
  #pragma unroll
  for (int p = 0; p < 2; p++){
    if (p == 1){                                // second half of V under pass 1
      #pragma unroll
      for (int ks = 0; ks < 8; ks++){
        const int j0v = (kh2 * 16 + ks + 8) * 32;
        vfb[ks] = ld8(V + (size_t)(d0 + l15) * cT + j0v + lq * 8);
      }
    }
    const int i = p * 8 + wave;
    const int qrow = q0 + i;
    const unsigned int* bmr = bm + ((size_t)b * cT + qrow) * 32;
    const int xr = ((i >> 2) & 3) << 3;
    float vals[16];
    float mx = -INFINITY;
    #pragma unroll
    for (int ii = 0; ii < 4; ii++){
      const int j0 = lane * 4 + ii * 256;
      const unsigned int mw = bmr[(lane >> 3) + ii * 8] >> (4 * (lane & 7));
      const floatx4 sv = *(const floatx4*)&sc[i * cT + (j0 ^ xr)];
      #pragma unroll
      for (int tt = 0; tt < 4; tt++){
        float s = sv[tt];
        if (((mw >> tt) & 1u) == 0u) s = -INFINITY;
        vals[ii * 4 + tt] = s;
        mx = fmaxf(mx, s);
      }
    }
    #pragma unroll
    for (int o = 32; o; o >>= 1) mx = fmaxf(mx, __shfl_xor(mx, o));
    float sum = 0.f;
    #pragma unroll
    for (int ii = 0; ii < 16; ii++){
      const float e = (vals[ii] == -INFINITY) ? 0.f : __expf(vals[ii] - mx);
      vals[ii] = e; sum += e;
    }
    #pragma unroll
    for (int o = 32; o; o >>= 1) sum += __shfl_xor(sum, o);
    const float ri = sum > 0.f ? 1.f / sum : 0.f;
    bar_lds();            // all sc reads of this pass's rows complete (lgkm only)
    float* arow = attn_out + ((size_t)bh * cT + qrow) * cT;
    unsigned short* prow_lds = pbuf + (size_t)i * PBS;
    #pragma unroll
    for (int ii = 0; ii < 4; ii++){
      const int j0 = lane * 4 + ii * 256;
      floatx4 pv;
      #pragma unroll
      for (int tt = 0; tt < 4; tt++) pv[tt] = vals[ii * 4 + tt] * ri;
      __builtin_nontemporal_store(pv, (floatx4*)(arow + j0));
      const unsigned int wlo = (unsigned int)f2bf(pv[0]) | ((unsigned int)f2bf(pv[1]) << 16);
      const unsigned int whi = (unsigned int)f2bf(pv[2]) | ((unsigned int)f2bf(pv[3]) << 16);
      *(unsigned long long*)(prow_lds + j0) =
          (unsigned long long)wlo | ((unsigned long long)whi << 32);
    }
  }
  bar_lds();

  // ---- phase 4: O = P V entirely from prefetched V registers ----
  floatx4 acc = (floatx4){0.f, 0.f, 0.f, 0.f};
  #pragma unroll
  for (int ks = 0; ks < 8; ks++){
    const int j0 = (kh2 * 16 + ks) * 32;
    const short8 af = ld8(pbuf + l15 * PBS + j0 + lq * 8);
    acc = MFMA16(af, vfr[ks], acc);
  }
  #pragma unroll
  for (int ks = 8; ks < 16; ks++){
    const int j0 = (kh2 * 16 + ks) * 32;
    const short8 af = ld8(pbuf + l15 * PBS + j0 + lq * 8);
    acc = MFMA16(af, vfb[ks - 8], acc);
  }
  // combine halves via 4 KiB LDS scratch past the pbuf overlay (byte 40960)
  float* red4 = sc + 10240;
  if (kh2 == 1) *(floatx4*)(red4 + ((wave & 3) * 256 + lane * 4)) = acc;
  bar_lds();
  if (kh2 == 0){
    acc += *(const floatx4*)(red4 + ((wave & 3) * 256 + lane * 4));
    #pragma unroll
    for (int r = 0; r < 4; r++){
      const int i = lq * 4 + r;
      out_h[((size_t)b * cT + q0 + i) * cD + h * cDK + d0 + l15] = f2bf(acc[r]);
    }
  }
}

// ---------------- host launcher ----------------
extern "C" void kernel_launch(void* const* d_in, const int* in_sizes, int n_in,
                              void* d_out, int out_size, void* d_ws, size_t ws_size,
                              hipStream_t stream)
{
  const float* q    = (const float*)d_in[0];
  const float* k    = (const float*)d_in[1];
  const float* v    = (const float*)d_in[2];
  const float* pe   = (const float*)d_in[3];
  const int*   mask = (const int*)d_in[4];
  const float* lnqg = (const float*)d_in[5];
  const float* lnqb = (const float*)d_in[6];
  const float* lnkg = (const float*)d_in[7];
  const float* lnkb = (const float*)d_in[8];
  const float* lnvg = (const float*)d_in[9];
  const float* lnvb = (const float*)d_in[10];
  const float* wq   = (const float*)d_in[11];
  const float* wk   = (const float*)d_in[12];
  const float* wv   = (const float*)d_in[13];
  const float* wpos = (const float*)d_in[14];
  const float* wfc  = (const float*)d_in[15];
  const float* pbu  = (const float*)d_in[16];
  const float* pbv  = (const float*)d_in[17];

  float* out_f  = (float*)d_out;                       // [8,1024,512] f32
  float* attn_f = out_f + (size_t)8 * 1024 * 512;      // [8,8,1024,1024] f32, 268 MB

  // --- scratch dead before attn_kernel lives inside the attn output region ---
  unsigned char* scr = (unsigned char*)attn_f;
  size_t soff = 0;
  auto salloc = [&](size_t bytes){ void* p = scr + soff; soff += (bytes + 255) & ~(size_t)255; return p; };
  unsigned short* qn   = (unsigned short*)salloc((size_t)8192 * 512 * 2);  // qn,kn,vn consecutive
  unsigned short* kn   = (unsigned short*)salloc((size_t)8192 * 512 * 2);
  unsigned short* vn   = (unsigned short*)salloc((size_t)8192 * 512 * 2);
  unsigned short* pe_b = (unsigned short*)salloc((size_t)2047 * 512 * 2);
  (void)kn; (void)vn;

  // --- workspace: buffers that live across / after attn_kernel (~46 MB) ---
  unsigned char* ws = (unsigned char*)d_ws;
  size_t off = 0;
  auto alloc = [&](size_t bytes){ void* p = ws + off; off += (bytes + 255) & ~(size_t)255; return p; };
  unsigned short* w5_b = (unsigned short*)alloc(5 * 512 * 512 * 2);        // wq,wk,wv,wpos,wfc
  unsigned short* qhb  = (unsigned short*)alloc((size_t)8192 * 512 * 2);   // qhb,khb,vhb consecutive
  unsigned short* khb  = (unsigned short*)alloc((size_t)8192 * 512 * 2);
  unsigned short* vhb  = (unsigned short*)alloc((size_t)8192 * 512 * 2);
  unsigned short* vtb  = (unsigned short*)alloc((size_t)8192 * 512 * 2);   // [B,H,64,T]
  unsigned short* ppb  = (unsigned short*)alloc((size_t)8 * 2047 * 64 * 2);// [H,P,64]
  float*          vbias= (float*)alloc((size_t)8 * 2047 * 4);              // [H,P]
  unsigned short* ohb  = (unsigned short*)alloc((size_t)8192 * 512 * 2);   // [B,T,512]
  unsigned int*   bmask= (unsigned int*)alloc((size_t)8192 * 32 * 4);      // [B,T,32]
  (void)ws_size; (void)n_in; (void)in_sizes; (void)out_size;

  Ptr5 c5; c5.p[0] = wq; c5.p[1] = wk; c5.p[2] = wv; c5.p[3] = wpos; c5.p[4] = wfc;
  cast5_kernel<<<5120, 256, 0, stream>>>(c5, w5_b);
  cast1_kernel<<<4094, 256, 0, stream>>>(pe, pe_b, 2047 * 512);
  maskbits_kernel<<<2048, 256, 0, stream>>>(mask, bmask);

  LN3 l3;
  l3.x[0] = q; l3.x[1] = k; l3.x[2] = v;
  l3.g[0] = lnqg; l3.g[1] = lnkg; l3.g[2] = lnvg;
  l3.b[0] = lnqb; l3.b[1] = lnkb; l3.b[2] = lnvb;
  l3.y[0] = qn; l3.y[1] = kn; l3.y[2] = vn;
  ln3_kernel<<<dim3(4096, 3), 256, 0, stream>>>(l3);

  // fused QKV projections (z=0:q scaled by 1/8 with pos_bias_u folded in, z=1:k, z=2:v)
  gemm512_kernel<<<dim3(4, 64, 3), 256, 0, stream>>>(qn, w5_b, 8192, 0, 0.125f,
                                                     qhb, nullptr, nullptr, pbu);
  gemm512_kernel<<<dim3(4, 16, 1), 256, 0, stream>>>(pe_b, w5_b + 3 * 262144, 2047, 1, 1.0f,
                                                     ppb, nullptr, nullptr, nullptr);

  transpose_v_kernel<<<dim3(64, 16), 256, 0, stream>>>(vhb, vtb);

  // bd bias uses (pos_bias_v - pos_bias_u) since qh already carries +pos_bias_u
  dot_bias_kernel<<<4094, 256, 0, stream>>>(ppb, pbv, pbu, vbias, 16376, 2047, 0.125f);

  attn_kernel<<<dim3(64, 64), 512, 0, stream>>>(qhb, khb, vtb, ppb, vbias,
                                                bmask, attn_f, ohb);

  gemm512_kernel<<<dim3(4, 64, 1), 256, 0, stream>>>(ohb, w5_b + 4 * 262144, 8192, 2, 1.0f,
                                                     nullptr, out_f, q, nullptr);
}

// Round 6
// 624.319 us; speedup vs baseline: 1.4471x; 1.0756x over previous
//
#include <hip/hip_runtime.h>

constexpr int cT  = 1024;
constexpr int cD  = 512;
constexpr int cDK = 64;
constexpr int cP  = 2047;
constexpr int PBS = 1040;   // bf16 prob-buffer row stride (pad 16 -> +8 banks/row)

typedef __attribute__((ext_vector_type(8))) short short8;
typedef __attribute__((ext_vector_type(4))) float floatx4;

#define MFMA16(a,b,c) __builtin_amdgcn_mfma_f32_16x16x32_bf16((a),(b),(c),0,0,0)
// swizzle keyed on i>>2 (varies across lanes within a store), not i&3 (constant)
// XORs only bit 3 of j -> 4-aligned j-groups stay contiguous (b128-safe)
#define SWZ(i,j) ((j) ^ ((((i) >> 2) & 3) << 3))

// barrier that does NOT drain vmcnt: LDS ordering only.
__device__ __forceinline__ void bar_lds(){
  asm volatile("s_waitcnt lgkmcnt(0)\n\ts_barrier" ::: "memory");
}
// full drain barrier for the gemm double-buffer (stage must land before reads)
__device__ __forceinline__ void bar_vm(){
  asm volatile("s_waitcnt vmcnt(0)\n\ts_barrier" ::: "memory");
}

__device__ __forceinline__ unsigned short f2bf(float f){
  union { float f; unsigned int u; } x; x.f = f;
  unsigned int r = x.u + 0x7fffu + ((x.u >> 16) & 1u);   // RNE
  return (unsigned short)(r >> 16);
}
__device__ __forceinline__ float bf2f(unsigned short h){
  union { unsigned int u; float f; } x; x.u = ((unsigned int)h) << 16;
  return x.f;
}
__device__ __forceinline__ short8 ld8(const unsigned short* p){
  return *(const short8*)p;
}
// async global->LDS, 16 B per lane. LDS dest must be wave-uniform base (HW adds lane*16).
__device__ __forceinline__ void gl_lds16(const unsigned short* g, unsigned short* l){
  __builtin_amdgcn_global_load_lds(
      (const __attribute__((address_space(1))) unsigned int*)g,
      (__attribute__((address_space(3))) unsigned int*)l, 16, 0, 0);
}

// ---------------- LayerNorm x3 + cast to bf16 (float4 loads, 2 rows/block) ----------------
struct LN3 { const float* x[3]; const float* g[3]; const float* b[3]; unsigned short* y[3]; };
__global__ void __launch_bounds__(256) ln3_kernel(LN3 a)
{
  __shared__ float red[8];                      // [half][wave-in-half][s,sq]
  const int z = blockIdx.y;
  const int half = threadIdx.x >> 7;            // 0,1 -> row within block
  const int r = blockIdx.x * 2 + half;
  const int tid = threadIdx.x & 127;            // 128 threads per row, float4 each
  const float* x = a.x[z]; const float* g = a.g[z]; const float* b = a.b[z];
  unsigned short* y = a.y[z];
  const float4 v = ((const float4*)(x + (size_t)r * cD))[tid];
  float s  = v.x + v.y + v.z + v.w;
  float sq = v.x * v.x + v.y * v.y + v.z * v.z + v.w * v.w;
  #pragma unroll
  for (int o = 32; o; o >>= 1){ s += __shfl_xor(s, o); sq += __shfl_xor(sq, o); }
  const int w = (threadIdx.x >> 6) & 1;         // wave within the row-half
  if ((threadIdx.x & 63) == 0){ red[half * 4 + w * 2] = s; red[half * 4 + w * 2 + 1] = sq; }
  __syncthreads();
  s  = red[half * 4]     + red[half * 4 + 2];
  sq = red[half * 4 + 1] + red[half * 4 + 3];
  const float mu  = s * (1.0f / cD);
  const float var = sq * (1.0f / cD) - mu * mu;
  const float rs  = rsqrtf(var + 1e-5f);
  const int c = tid * 4;
  const float4 gv = *(const float4*)(g + c);
  const float4 bv = *(const float4*)(b + c);
  const unsigned int o0 = (unsigned int)f2bf((v.x - mu) * rs * gv.x + bv.x)
                        | ((unsigned int)f2bf((v.y - mu) * rs * gv.y + bv.y) << 16);
  const unsigned int o1 = (unsigned int)f2bf((v.z - mu) * rs * gv.z + bv.z)
                        | ((unsigned int)f2bf((v.w - mu) * rs * gv.w + bv.w) << 16);
  ((uint2*)(y + (size_t)r * cD))[tid] = make_uint2(o0, o1);
}

// ---------------- f32 -> bf16 casts ----------------
struct Ptr5 { const float* p[5]; };
__global__ void __launch_bounds__(256) cast5_kernel(Ptr5 s, unsigned short* __restrict__ d){
  const int idx = blockIdx.x * 256 + threadIdx.x;          // 5 * 262144 total
  const int seg = idx >> 18, off = idx & 262143;
  d[idx] = f2bf(s.p[seg][off]);
}
__global__ void __launch_bounds__(256) cast1_kernel(const float* __restrict__ s,
    unsigned short* __restrict__ d, int n){
  const int idx = blockIdx.x * 256 + threadIdx.x;
  if (idx < n) d[idx] = f2bf(s[idx]);
}

// ---------------- mask -> bitmask: bm[(b*T+t)*32 + w] bit (j&31) = mask!=0 ----------------
__global__ void __launch_bounds__(256) maskbits_kernel(
    const int* __restrict__ mask, unsigned int* __restrict__ bm)
{
  const int row = blockIdx.x * 4 + (threadIdx.x >> 6);
  const int lane = threadIdx.x & 63;
  #pragma unroll
  for (int ii = 0; ii < 16; ii++){
    const int m = mask[(size_t)row * cT + ii * 64 + lane];
    const unsigned long long bal = __ballot(m != 0);
    if (lane == 0)       bm[row * 32 + ii * 2]     = (unsigned int)bal;
    else if (lane == 32) bm[row * 32 + ii * 2 + 1] = (unsigned int)(bal >> 32);
  }
}

// ---------------- GEMM: Y[r][o] = scale * sum_k A[r][k] * W[o][k]; K=N=512 ------------
// m97-style: 128x128 tile, BK=32, double-buffered LDS via global_load_lds(16B).
// gload_lds writes linearly (lane*16), so bank-conflict-free ds_read is achieved by
// T21: pre-swizzled GLOBAL source (cg_log = (l&3)^((l>>3)&3), free within each 64B
// segment) + the same XOR on the read side (lq ^ ((l15>>1)&3)).
// mode 0, z==0: adds addq[col] to acc BEFORE scaling (folds pos_bias_u into qh).
__global__ void __launch_bounds__(256, 4) gemm512_kernel(
    const unsigned short* __restrict__ A0, const unsigned short* __restrict__ W0,
    int M, int mode, float scaleA, unsigned short* __restrict__ outb,
    float* __restrict__ outf, const float* __restrict__ residual,
    const float* __restrict__ addq)
{
  __shared__ __align__(16) unsigned short lsA[2][4096];   // [buf][128 rows][32 k]
  __shared__ __align__(16) unsigned short lsB[2][4096];
  const int z = blockIdx.z;
  const unsigned short* A = A0 + (size_t)z * 4194304;
  const unsigned short* W = W0 + (size_t)z * 262144;
  unsigned short* outz = outb ? outb + (size_t)z * 4194304 : outb;
  const float sA = (z == 0) ? scaleA : 1.0f;
  const int n0 = blockIdx.x * 128, m0 = blockIdx.y * 128;
  const int tid = threadIdx.x;
  const int wave = tid >> 6, lane = tid & 63;
  const int wr = wave >> 1, wc = wave & 1;
  const int l15 = lane & 15, lq = lane >> 4;
  const int srow = tid >> 2;                       // 0..63 staging row within issue
  const int scol = ((tid & 3) ^ ((tid >> 3) & 3)) * 8;  // inverse-swizzled source col
  const int xr4  = (l15 >> 1) & 3;                 // read-side swizzle key

  auto STAGE = [&](int k0, int buf){
    #pragma unroll
    for (int s = 0; s < 2; s++){
      gl_lds16(A + (size_t)(m0 + s * 64 + srow) * 512 + k0 + scol,
               &lsA[buf][s * 2048 + wave * 512]);
      gl_lds16(W + (size_t)(n0 + s * 64 + srow) * 512 + k0 + scol,
               &lsB[buf][s * 2048 + wave * 512]);
    }
  };

  floatx4 acc[4][4];
  #pragma unroll
  for (int i = 0; i < 4; i++)
    #pragma unroll
    for (int j = 0; j < 4; j++) acc[i][j] = (floatx4){0.f, 0.f, 0.f, 0.f};

  STAGE(0, 0);
  bar_vm();
  #pragma unroll 2
  for (int ks = 0; ks < 16; ks++){
    const int cur = ks & 1;
    if (ks < 15) STAGE((ks + 1) * 32, cur ^ 1);
    short8 af[4], bf[4];
    #pragma unroll
    for (int i = 0; i < 4; i++){
      af[i] = *(const short8*)&lsA[cur][(wr * 64 + i * 16 + l15) * 32 + ((lq ^ xr4) * 8)];
      bf[i] = *(const short8*)&lsB[cur][(wc * 64 + i * 16 + l15) * 32 + ((lq ^ xr4) * 8)];
    }
    #pragma unroll
    for (int i = 0; i < 4; i++)
      #pragma unroll
      for (int j = 0; j < 4; j++)
        acc[i][j] = MFMA16(af[i], bf[j], acc[i][j]);
    bar_vm();          // stage for ks+1 landed; all waves done reading buf[cur]
  }

  #pragma unroll
  for (int i = 0; i < 4; i++){
    #pragma unroll
    for (int j = 0; j < 4; j++){
      #pragma unroll
      for (int r = 0; r < 4; r++){
        const int row = m0 + wr * 64 + i * 16 + lq * 4 + r;
        const int col = n0 + wc * 64 + j * 16 + l15;
        if (row >= M) continue;
        float val = acc[i][j][r];
        if (mode == 0 && z == 0 && addq) val += addq[col];
        val *= sA;
        if (mode == 0){
          const int bb = row >> 10, t = row & 1023, h = col >> 6, d = col & 63;
          outz[(((size_t)(bb * 8 + h) * 1024 + t) << 6) + d] = f2bf(val);
        } else if (mode == 1){
          const int h = col >> 6, d = col & 63;
          outz[(((size_t)h * 2047 + row) << 6) + d] = f2bf(val);
        } else {
          const size_t idx = (size_t)row * 512 + col;
          outf[idx] = val + residual[idx];
        }
      }
    }
  }
}

// ---------------- V transpose: [BH,T,64] -> [BH,64,T] ----------------
__global__ void __launch_bounds__(256) transpose_v_kernel(
    const unsigned short* __restrict__ vh, unsigned short* __restrict__ vt)
{
  __shared__ unsigned short tile[64][65];
  const int bh = blockIdx.x, t0 = blockIdx.y * 64;
  const unsigned short* src = vh + ((size_t)bh * cT + t0) * cDK;
  #pragma unroll
  for (int i = 0; i < 16; i++){
    const int idx = threadIdx.x + i * 256;
    tile[idx >> 6][idx & 63] = src[idx];
  }
  __syncthreads();
  unsigned short* dst = vt + (size_t)bh * cDK * cT + t0;
  #pragma unroll
  for (int i = 0; i < 16; i++){
    const int idx = threadIdx.x + i * 256;
    const int d = idx >> 6, t = idx & 63;
    dst[(size_t)d * cT + t] = tile[t][d];
  }
}

// ---------------- per-key bias: out[row] = scale * dot64(bias-bias2, X[row]) ----------------
__global__ void __launch_bounds__(256) dot_bias_kernel(
    const unsigned short* __restrict__ X, const float* __restrict__ bias,
    const float* __restrict__ bias2, float* __restrict__ out,
    int rows, int hdiv, float scale)
{
  const int row = blockIdx.x * 4 + (threadIdx.x >> 6);
  const int lane = threadIdx.x & 63;
  if (row >= rows) return;
  const int h = (row / hdiv) & 7;
  float bv = bias[h * 64 + lane];
  if (bias2) bv -= bias2[h * 64 + lane];
  float s = bf2f(X[(size_t)row * 64 + lane]) * bv;
  #pragma unroll
  for (int o = 32; o; o >>= 1) s += __shfl_xor(s, o);
  if (lane == 0) out[row] = s * scale;
}

// ---------------- fused relpos attention: block = (b,h, 16 q-rows), 8 waves ----------------
// (unchanged from round 5 -- serves as the control dispatch this round)
__global__ void __launch_bounds__(512, 4) attn_kernel(
    const unsigned short* __restrict__ qh, const unsigned short* __restrict__ kh,
    const unsigned short* __restrict__ vt, const unsigned short* __restrict__ pproj,
    const float* __restrict__ vbias, const unsigned int* __restrict__ bm,
    float* __restrict__ attn_out, unsigned short* __restrict__ out_h)
{
  __shared__ float sc[16 * cT];                 // 64 KiB f32 scores
  unsigned short* pbuf = (unsigned short*)sc;   // bf16 [16][PBS] overlay (33,248 B), used after
  const int bh = blockIdx.x, b = bh >> 3, h = bh & 7;
  const int q0 = blockIdx.y * 16;
  const int wave = threadIdx.x >> 6, lane = threadIdx.x & 63;
  const int l15 = lane & 15, lq = lane >> 4;
  const unsigned short* Q  = qh + (size_t)bh * cT * cDK;
  const unsigned short* Kp = kh + (size_t)bh * cT * cDK;
  const unsigned short* Pt = pproj + (size_t)h * cP * cDK;
  const float* vb = vbias + (size_t)h * cP;

  const short8 qf0 = ld8(Q + (size_t)(q0 + l15) * cDK + lq * 8);
  const short8 qf1 = ld8(Q + (size_t)(q0 + l15) * cDK + 32 + lq * 8);

  // ---- phase 1: ac = Q K^T -> LDS (2-way banks via SWZ); staged loads ----
  {
    short8 k0a[8], k1a[8];
    #pragma unroll
    for (int t = 0; t < 8; t++){
      const int jt = wave + t * 8;
      k0a[t] = ld8(Kp + (size_t)(jt * 16 + l15) * cDK + lq * 8);
      k1a[t] = ld8(Kp + (size_t)(jt * 16 + l15) * cDK + 32 + lq * 8);
    }
    #pragma unroll
    for (int t = 0; t < 8; t++){
      const int jt = wave + t * 8;
      floatx4 acc = (floatx4){0.f, 0.f, 0.f, 0.f};
      acc = MFMA16(qf0, k0a[t], acc);
      acc = MFMA16(qf1, k1a[t], acc);
      const int jb = jt * 16 + l15;
      #pragma unroll
      for (int r = 0; r < 4; r++){
        const int i = lq * 4 + r;
        sc[i * cT + (jb ^ (lq << 3))] = acc[r];
      }
    }
  }
  bar_lds();

  // ---- phase 2: bd window GEMM + vb bias, diagonal scatter-add  j = c - 15 + i ----
  const int w0 = (cT - 1) - q0 - 15;
  {
    short8 p0a[8], p1a[8];
    float vba[8];
    #pragma unroll
    for (int t = 0; t < 8; t++){
      const int c = (wave + t * 8) * 16 + l15;
      int prow = w0 + c; if (prow > cP - 1) prow = cP - 1;
      p0a[t] = ld8(Pt + (size_t)prow * cDK + lq * 8);
      p1a[t] = ld8(Pt + (size_t)prow * cDK + 32 + lq * 8);
      vba[t] = vb[prow];
    }
    #pragma unroll
    for (int t = 0; t < 8; t++){
      const int c = (wave + t * 8) * 16 + l15;
      floatx4 acc = (floatx4){0.f, 0.f, 0.f, 0.f};
      acc = MFMA16(qf0, p0a[t], acc);
      acc = MFMA16(qf1, p1a[t], acc);
      #pragma unroll
      for (int r = 0; r < 4; r++){
        const int i = lq * 4 + r;
        const int j = c - 15 + i;
        if (j >= 0 && j < cT) sc[i * cT + SWZ(i, j)] += acc[r] + vba[t];
      }
    }
  }
  if (wave == 0){                               // tail column-tile ct=64
    const int c = 1024 + l15;
    int prow = w0 + c; if (prow > cP - 1) prow = cP - 1;
    const short8 pf0 = ld8(Pt + (size_t)prow * cDK + lq * 8);
    const short8 pf1 = ld8(Pt + (size_t)prow * cDK + 32 + lq * 8);
    const float vbv = vb[prow];
    floatx4 acc = (floatx4){0.f, 0.f, 0.f, 0.f};
    acc = MFMA16(qf0, pf0, acc);
    acc = MFMA16(qf1, pf1, acc);
    #pragma unroll
    for (int r = 0; r < 4; r++){
      const int i = lq * 4 + r;
      const int j = c - 15 + i;
      if (j >= 0 && j < cT) sc[i * cT + SWZ(i, j)] += acc[r] + vbv;
    }
  }
  bar_lds();

  // ---- V prefetch: first 8 of 16 phase-4 fragments (32 VGPR) ----
  const unsigned short* V = vt + (size_t)bh * cDK * cT;
  const int d0 = (wave & 3) * 16;
  const int kh2 = wave >> 2;                    // 0: keys 0-511, 1: keys 512-1023
  short8 vfr[8], vfb[8];
  #pragma unroll
  for (int ks = 0; ks < 8; ks++){
    const int j0v = (kh2 * 16 + ks) * 32;
    vfr[ks] = ld8(V + (size_t)(d0 + l15) * cT + j0v + lq * 8);
  }

  // ---- phase 3: masked softmax, 2 passes (read | barrier | write), 8 rows/pass ----
  #pragma unroll
  for (int p = 0; p < 2; p++){
    if (p == 1){                                // second half of V under pass 1
      #pragma unroll
      for (int ks = 0; ks < 8; ks++){
        const int j0v = (kh2 * 16 + ks + 8) * 32;
        vfb[ks] = ld8(V + (size_t)(d0 + l15) * cT + j0v + lq * 8);
      }
    }
    const int i = p * 8 + wave;
    const int qrow = q0 + i;
    const unsigned int* bmr = bm + ((size_t)b * cT + qrow) * 32;
    const int xr = ((i >> 2) & 3) << 3;
    float vals[16];
    float mx = -INFINITY;
    #pragma unroll
    for (int ii = 0; ii < 4; ii++){
      const int j0 = lane * 4 + ii * 256;
      const unsigned int mw = bmr[(lane >> 3) + ii * 8] >> (4 * (lane & 7));
      const floatx4 sv = *(const floatx4*)&sc[i * cT + (j0 ^ xr)];
      #pragma unroll
      for (int tt = 0; tt < 4; tt++){
        float s = sv[tt];
        if (((mw >> tt) & 1u) == 0u) s = -INFINITY;
        vals[ii * 4 + tt] = s;
        mx = fmaxf(mx, s);
      }
    }
    #pragma unroll
    for (int o = 32; o; o >>= 1) mx = fmaxf(mx, __shfl_xor(mx, o));
    float sum = 0.f;
    #pragma unroll
    for (int ii = 0; ii < 16; ii++){
      const float e = (vals[ii] == -INFINITY) ? 0.f : __expf(vals[ii] - mx);
      vals[ii] = e; sum += e;
    }
    #pragma unroll
    for (int o = 32; o; o >>= 1) sum += __shfl_xor(sum, o);
    const float ri = sum > 0.f ? 1.f / sum : 0.f;
    bar_lds();            // all sc reads of this pass's rows complete (lgkm only)
    float* arow = attn_out + ((size_t)bh * cT + qrow) * cT;
    unsigned short* prow_lds = pbuf + (size_t)i * PBS;
    #pragma unroll
    for (int ii = 0; ii < 4; ii++){
      const int j0 = lane * 4 + ii * 256;
      floatx4 pv;
      #pragma unroll
      for (int tt = 0; tt < 4; tt++) pv[tt] = vals[ii * 4 + tt] * ri;
      __builtin_nontemporal_store(pv, (floatx4*)(arow + j0));
      const unsigned int wlo = (unsigned int)f2bf(pv[0]) | ((unsigned int)f2bf(pv[1]) << 16);
      const unsigned int whi = (unsigned int)f2bf(pv[2]) | ((unsigned int)f2bf(pv[3]) << 16);
      *(unsigned long long*)(prow_lds + j0) =
          (unsigned long long)wlo | ((unsigned long long)whi << 32);
    }
  }
  bar_lds();

  // ---- phase 4: O = P V entirely from prefetched V registers ----
  floatx4 acc = (floatx4){0.f, 0.f, 0.f, 0.f};
  #pragma unroll
  for (int ks = 0; ks < 8; ks++){
    const int j0 = (kh2 * 16 + ks) * 32;
    const short8 af = ld8(pbuf + l15 * PBS + j0 + lq * 8);
    acc = MFMA16(af, vfr[ks], acc);
  }
  #pragma unroll
  for (int ks = 8; ks < 16; ks++){
    const int j0 = (kh2 * 16 + ks) * 32;
    const short8 af = ld8(pbuf + l15 * PBS + j0 + lq * 8);
    acc = MFMA16(af, vfb[ks - 8], acc);
  }
  // combine halves via 4 KiB LDS scratch past the pbuf overlay (byte 40960)
  float* red4 = sc + 10240;
  if (kh2 == 1) *(floatx4*)(red4 + ((wave & 3) * 256 + lane * 4)) = acc;
  bar_lds();
  if (kh2 == 0){
    acc += *(const floatx4*)(red4 + ((wave & 3) * 256 + lane * 4));
    #pragma unroll
    for (int r = 0; r < 4; r++){
      const int i = lq * 4 + r;
      out_h[((size_t)b * cT + q0 + i) * cD + h * cDK + d0 + l15] = f2bf(acc[r]);
    }
  }
}

// ---------------- host launcher ----------------
extern "C" void kernel_launch(void* const* d_in, const int* in_sizes, int n_in,
                              void* d_out, int out_size, void* d_ws, size_t ws_size,
                              hipStream_t stream)
{
  const float* q    = (const float*)d_in[0];
  const float* k    = (const float*)d_in[1];
  const float* v    = (const float*)d_in[2];
  const float* pe   = (const float*)d_in[3];
  const int*   mask = (const int*)d_in[4];
  const float* lnqg = (const float*)d_in[5];
  const float* lnqb = (const float*)d_in[6];
  const float* lnkg = (const float*)d_in[7];
  const float* lnkb = (const float*)d_in[8];
  const float* lnvg = (const float*)d_in[9];
  const float* lnvb = (const float*)d_in[10];
  const float* wq   = (const float*)d_in[11];
  const float* wk   = (const float*)d_in[12];
  const float* wv   = (const float*)d_in[13];
  const float* wpos = (const float*)d_in[14];
  const float* wfc  = (const float*)d_in[15];
  const float* pbu  = (const float*)d_in[16];
  const float* pbv  = (const float*)d_in[17];

  float* out_f  = (float*)d_out;                       // [8,1024,512] f32
  float* attn_f = out_f + (size_t)8 * 1024 * 512;      // [8,8,1024,1024] f32, 268 MB

  // --- scratch dead before attn_kernel lives inside the attn output region ---
  unsigned char* scr = (unsigned char*)attn_f;
  size_t soff = 0;
  auto salloc = [&](size_t bytes){ void* p = scr + soff; soff += (bytes + 255) & ~(size_t)255; return p; };
  unsigned short* qn   = (unsigned short*)salloc((size_t)8192 * 512 * 2);  // qn,kn,vn consecutive
  unsigned short* kn   = (unsigned short*)salloc((size_t)8192 * 512 * 2);
  unsigned short* vn   = (unsigned short*)salloc((size_t)8192 * 512 * 2);
  unsigned short* pe_b = (unsigned short*)salloc((size_t)2047 * 512 * 2);
  (void)kn; (void)vn;

  // --- workspace: buffers that live across / after attn_kernel (~46 MB) ---
  unsigned char* ws = (unsigned char*)d_ws;
  size_t off = 0;
  auto alloc = [&](size_t bytes){ void* p = ws + off; off += (bytes + 255) & ~(size_t)255; return p; };
  unsigned short* w5_b = (unsigned short*)alloc(5 * 512 * 512 * 2);        // wq,wk,wv,wpos,wfc
  unsigned short* qhb  = (unsigned short*)alloc((size_t)8192 * 512 * 2);   // qhb,khb,vhb consecutive
  unsigned short* khb  = (unsigned short*)alloc((size_t)8192 * 512 * 2);
  unsigned short* vhb  = (unsigned short*)alloc((size_t)8192 * 512 * 2);
  unsigned short* vtb  = (unsigned short*)alloc((size_t)8192 * 512 * 2);   // [B,H,64,T]
  unsigned short* ppb  = (unsigned short*)alloc((size_t)8 * 2047 * 64 * 2);// [H,P,64]
  float*          vbias= (float*)alloc((size_t)8 * 2047 * 4);              // [H,P]
  unsigned short* ohb  = (unsigned short*)alloc((size_t)8192 * 512 * 2);   // [B,T,512]
  unsigned int*   bmask= (unsigned int*)alloc((size_t)8192 * 32 * 4);      // [B,T,32]
  (void)ws_size; (void)n_in; (void)in_sizes; (void)out_size;

  Ptr5 c5; c5.p[0] = wq; c5.p[1] = wk; c5.p[2] = wv; c5.p[3] = wpos; c5.p[4] = wfc;
  cast5_kernel<<<5120, 256, 0, stream>>>(c5, w5_b);
  cast1_kernel<<<4094, 256, 0, stream>>>(pe, pe_b, 2047 * 512);
  maskbits_kernel<<<2048, 256, 0, stream>>>(mask, bmask);

  LN3 l3;
  l3.x[0] = q; l3.x[1] = k; l3.x[2] = v;
  l3.g[0] = lnqg; l3.g[1] = lnkg; l3.g[2] = lnvg;
  l3.b[0] = lnqb; l3.b[1] = lnkb; l3.b[2] = lnvb;
  l3.y[0] = qn; l3.y[1] = kn; l3.y[2] = vn;
  ln3_kernel<<<dim3(4096, 3), 256, 0, stream>>>(l3);

  // fused QKV projections (z=0:q scaled by 1/8 with pos_bias_u folded in, z=1:k, z=2:v)
  gemm512_kernel<<<dim3(4, 64, 3), 256, 0, stream>>>(qn, w5_b, 8192, 0, 0.125f,
                                                     qhb, nullptr, nullptr, pbu);
  gemm512_kernel<<<dim3(4, 16, 1), 256, 0, stream>>>(pe_b, w5_b + 3 * 262144, 2047, 1, 1.0f,
                                                     ppb, nullptr, nullptr, nullptr);

  transpose_v_kernel<<<dim3(64, 16), 256, 0, stream>>>(vhb, vtb);

  // bd bias uses (pos_bias_v - pos_bias_u) since qh already carries +pos_bias_u
  dot_bias_kernel<<<4094, 256, 0, stream>>>(ppb, pbv, pbu, vbias, 16376, 2047, 0.125f);

  attn_kernel<<<dim3(64, 64), 512, 0, stream>>>(qhb, khb, vtb, ppb, vbias,
                                                bmask, attn_f, ohb);

  gemm512_kernel<<<dim3(4, 64, 1), 256, 0, stream>>>(ohb, w5_b + 4 * 262144, 8192, 2, 1.0f,
                                                     nullptr, out_f, q, nullptr);
}